// Round 4
// baseline (2870.919 us; speedup 1.0000x reference)
//
#include <hip/hip_runtime.h>
#include <hip/hip_bf16.h>
#include <math.h>

// ---------------------------------------------------------------------------
// GATv2 x2 + global_add_pool + MLP head, fp32.
// k_xw: LDS-tiled GEMM. k_alpha/k_selfalpha: head-split (blockIdx.y = head)
// so per-lane We slice = 32 regs (asm-pinned), full occupancy, no sink/spill.
// ---------------------------------------------------------------------------

__device__ __forceinline__ unsigned enc_f(float f) {
    int b = __float_as_int(f);
    unsigned u = (unsigned)b;
    return (b >= 0) ? (u | 0x80000000u) : ~u;
}
__device__ __forceinline__ float dec_f(unsigned u) {
    int b = (u & 0x80000000u) ? (int)(u & 0x7fffffffu) : (int)~u;
    return __int_as_float(b);
}

__global__ void k_deg(const int* __restrict__ dst, int E, int* __restrict__ deg) {
    int e = blockIdx.x * blockDim.x + threadIdx.x;
    if (e < E) atomicAdd(&deg[dst[e]], 1);
}

// ---- multi-block exclusive scan: deg[N] -> row_ptr[N+1], woff[N] ----------
__global__ void k_scan1(const int* __restrict__ deg, int N,
                        int* __restrict__ incl, int* __restrict__ bsum) {
    __shared__ int ws4[4];
    const int tid = threadIdx.x;
    const int lane = tid & 63, w = tid >> 6;
    const int base = blockIdx.x * 2048;
    int v[8];
    int s = 0;
#pragma unroll
    for (int j = 0; j < 8; ++j) {
        int i = base + tid * 8 + j;
        v[j] = (i < N) ? deg[i] : 0;
        s += v[j];
    }
    int ps = s;
#pragma unroll
    for (int off = 1; off < 64; off <<= 1) {
        int t = __shfl_up(ps, off);
        if (lane >= off) ps += t;
    }
    if (lane == 63) ws4[w] = ps;
    __syncthreads();
    int woffs = 0;
#pragma unroll
    for (int k = 0; k < 4; ++k)
        if (k < w) woffs += ws4[k];
    int run = ps - s + woffs;
#pragma unroll
    for (int j = 0; j < 8; ++j) {
        run += v[j];
        int i = base + tid * 8 + j;
        if (i < N) incl[i] = run;
    }
    if (tid == 255) bsum[blockIdx.x] = run;
}

__global__ void k_scan2(int* __restrict__ bsum, int nb) {
    if (threadIdx.x == 0) {
        int c = 0;
        for (int k = 0; k < nb; ++k) { int t = bsum[k]; bsum[k] = c; c += t; }
    }
}

__global__ void k_scan3(const int* __restrict__ incl, const int* __restrict__ deg,
                        const int* __restrict__ boff, int N,
                        int* __restrict__ row_ptr, int* __restrict__ woff) {
    int i = blockIdx.x * blockDim.x + threadIdx.x;
    if (i < N) {
        int v = incl[i] + boff[i >> 11];
        row_ptr[i + 1] = v;
        woff[i] = v - deg[i];
        if (i == 0) row_ptr[0] = 0;
    }
}

__global__ void k_scatter(const int* __restrict__ dst, int E,
                          int* __restrict__ woff, int* __restrict__ cidx) {
    int e = blockIdx.x * blockDim.x + threadIdx.x;
    if (e < E) { int p = atomicAdd(&woff[dst[e]], 1); cidx[p] = e; }
}

__global__ void k_easum(const float* __restrict__ ea, const int* __restrict__ dst,
                        int E, float* __restrict__ easum) {
    int t = blockIdx.x * blockDim.x + threadIdx.x;
    int e = t >> 5, k = t & 31;
    if (e < E) atomicAdd(&easum[(size_t)dst[e] * 32 + k], ea[(size_t)e * 32 + k]);
}

// ---- LDS-tiled GEMM: out{l,r}[n][col] = in[n][:128] . W{l,r}[:, col] + b ----
template <int HC>
__global__ __launch_bounds__(256, 2) void k_xw(
        const float* __restrict__ in, int N,
        const float* __restrict__ Wl, const float* __restrict__ bl,
        const float* __restrict__ Wr, const float* __restrict__ br,
        float* __restrict__ outl, float* __restrict__ outr) {
    __shared__ float Xs[128][68];  // [k][row], +4 pad
    __shared__ float Ws[128][64];  // [k][col]
    const int tid = threadIdx.x;
    const int m0 = blockIdx.x * 64;
    const int cc = blockIdx.y;

#pragma unroll
    for (int t = 0; t < 8; ++t) {
        int idx4 = tid + t * 256;
        int r = idx4 >> 5, k4 = idx4 & 31;
        int n = m0 + r;
        float4 v = make_float4(0.f, 0.f, 0.f, 0.f);
        if (n < N) v = ((const float4*)in)[(size_t)n * 32 + k4];
        Xs[k4 * 4 + 0][r] = v.x;
        Xs[k4 * 4 + 1][r] = v.y;
        Xs[k4 * 4 + 2][r] = v.z;
        Xs[k4 * 4 + 3][r] = v.w;
    }

    const int rm = tid >> 4, rn = tid & 15;
    float acc[4][4];

#pragma unroll
    for (int mat = 0; mat < 2; ++mat) {
        const float* W = mat ? Wr : Wl;
        const float* b = mat ? br : bl;
        float* out = mat ? outr : outl;
        __syncthreads();
#pragma unroll
        for (int i = tid; i < 128 * 64; i += 256) {
            int k = i >> 6, c = i & 63;
            Ws[k][c] = W[(size_t)k * HC + cc * 64 + c];
        }
        __syncthreads();
#pragma unroll
        for (int i = 0; i < 4; ++i)
#pragma unroll
            for (int j = 0; j < 4; ++j) acc[i][j] = 0.f;
#pragma unroll 8
        for (int k = 0; k < 128; ++k) {
            float4 a = *(const float4*)&Xs[k][rm * 4];
            float4 bv = *(const float4*)&Ws[k][rn * 4];
            acc[0][0] += a.x * bv.x; acc[0][1] += a.x * bv.y;
            acc[0][2] += a.x * bv.z; acc[0][3] += a.x * bv.w;
            acc[1][0] += a.y * bv.x; acc[1][1] += a.y * bv.y;
            acc[1][2] += a.y * bv.z; acc[1][3] += a.y * bv.w;
            acc[2][0] += a.z * bv.x; acc[2][1] += a.z * bv.y;
            acc[2][2] += a.z * bv.z; acc[2][3] += a.z * bv.w;
            acc[3][0] += a.w * bv.x; acc[3][1] += a.w * bv.y;
            acc[3][2] += a.w * bv.z; acc[3][3] += a.w * bv.w;
        }
        float4 bb = *(const float4*)&b[cc * 64 + rn * 4];
#pragma unroll
        for (int i = 0; i < 4; ++i) {
            int n = m0 + rm * 4 + i;
            if (n < N) {
                float4 o = make_float4(acc[i][0] + bb.x, acc[i][1] + bb.y,
                                       acc[i][2] + bb.z, acc[i][3] + bb.w);
                *(float4*)&out[(size_t)n * HC + cc * 64 + rn * 4] = o;
            }
        }
    }
}

// dot of 32-wide ea vector with pinned weight slice
__device__ __forceinline__ float dot32(const float4* __restrict__ ep,
                                       const float* __restrict__ w) {
    float ee = 0.f;
#pragma unroll
    for (int q = 0; q < 8; ++q) {
        float4 v = ep[q];
        ee += v.x * w[4 * q + 0];
        ee += v.y * w[4 * q + 1];
        ee += v.z * w[4 * q + 2];
        ee += v.w * w[4 * q + 3];
    }
    return ee;
}

// self-loop logits, head-split: blockIdx.y = head
template <int H>
__global__ __launch_bounds__(256, 4) void k_selfalpha(
        const float* __restrict__ xl, const float* __restrict__ xr,
        const float* __restrict__ easum, const int* __restrict__ deg,
        const float* __restrict__ We, const float* __restrict__ att,
        int Nn, float* __restrict__ aself, unsigned* __restrict__ amax) {
    constexpr int HC = H * 64;
    const int h = blockIdx.y;
    const int lane = threadIdx.x & 63;
    const int n = (blockIdx.x * blockDim.x + threadIdx.x) >> 6;
    if (n >= Nn) return;
    float w[32];
#pragma unroll
    for (int k = 0; k < 32; ++k) w[k] = We[k * HC + h * 64 + lane];
#pragma unroll
    for (int k = 0; k < 32; ++k) asm volatile("" : "+v"(w[k]));
    const float attr = att[h * 64 + lane];
    int dg = deg[n];
    float inv = 1.f / (float)(dg > 0 ? dg : 1);
    float ee = dot32((const float4*)(easum + (size_t)n * 32), w);
    float m = xl[(size_t)n * HC + h * 64 + lane] + xr[(size_t)n * HC + h * 64 + lane]
            + ee * inv;
    m = m > 0.f ? m : 0.2f * m;
    float al = m * attr;
#pragma unroll
    for (int off = 1; off < 64; off <<= 1) al += __shfl_xor(al, off);
    if (lane == 0) {
        aself[(size_t)n * H + h] = al;
        atomicMax(&amax[(size_t)n * H + h], enc_f(al));
    }
}

// edge-parallel logits, head-split: blockIdx.y = head, 2-edge interleave
template <int H>
__global__ __launch_bounds__(256, 4) void k_alpha(
        const float* __restrict__ xl, const float* __restrict__ xr,
        const float* __restrict__ ea,
        const int* __restrict__ src, const int* __restrict__ dst, int E,
        const float* __restrict__ We, const float* __restrict__ att,
        float* __restrict__ alpha, unsigned* __restrict__ amax) {
    constexpr int HC = H * 64;
    constexpr int EPW = 8;
    const int h = blockIdx.y;
    const int lane = threadIdx.x & 63;
    const int wid = (blockIdx.x * blockDim.x + threadIdx.x) >> 6;
    float w[32];
#pragma unroll
    for (int k = 0; k < 32; ++k) w[k] = We[k * HC + h * 64 + lane];
#pragma unroll
    for (int k = 0; k < 32; ++k) asm volatile("" : "+v"(w[k]));
    const float attr = att[h * 64 + lane];
    const int e0 = wid * EPW;
    const int e1 = (e0 + EPW < E) ? e0 + EPW : E;
    int e = e0;
    for (; e + 1 < e1; e += 2) {
        int s0 = src[e], d0 = dst[e];
        int s1 = src[e + 1], d1 = dst[e + 1];
        float xl0 = xl[(size_t)s0 * HC + h * 64 + lane];
        float xr0 = xr[(size_t)d0 * HC + h * 64 + lane];
        float xl1 = xl[(size_t)s1 * HC + h * 64 + lane];
        float xr1 = xr[(size_t)d1 * HC + h * 64 + lane];
        float ee0 = dot32((const float4*)(ea + (size_t)e * 32), w);
        float ee1 = dot32((const float4*)(ea + (size_t)(e + 1) * 32), w);
        float m0 = xl0 + xr0 + ee0;
        float m1 = xl1 + xr1 + ee1;
        m0 = m0 > 0.f ? m0 : 0.2f * m0;
        m1 = m1 > 0.f ? m1 : 0.2f * m1;
        float a0 = m0 * attr, a1 = m1 * attr;
#pragma unroll
        for (int off = 1; off < 64; off <<= 1) {
            a0 += __shfl_xor(a0, off);
            a1 += __shfl_xor(a1, off);
        }
        if (lane == 0) {
            alpha[(size_t)e * H + h] = a0;
            atomicMax(&amax[(size_t)d0 * H + h], enc_f(a0));
            alpha[(size_t)(e + 1) * H + h] = a1;
            atomicMax(&amax[(size_t)d1 * H + h], enc_f(a1));
        }
    }
    if (e < e1) {
        int s0 = src[e], d0 = dst[e];
        float xl0 = xl[(size_t)s0 * HC + h * 64 + lane];
        float xr0 = xr[(size_t)d0 * HC + h * 64 + lane];
        float ee0 = dot32((const float4*)(ea + (size_t)e * 32), w);
        float m0 = xl0 + xr0 + ee0;
        m0 = m0 > 0.f ? m0 : 0.2f * m0;
        float a0 = m0 * attr;
#pragma unroll
        for (int off = 1; off < 64; off <<= 1) a0 += __shfl_xor(a0, off);
        if (lane == 0) {
            alpha[(size_t)e * H + h] = a0;
            atomicMax(&amax[(size_t)d0 * H + h], enc_f(a0));
        }
    }
}

// gather-CSR softmax aggregate: one wave per node, lane = channel
template <int H, bool RELU>
__global__ __launch_bounds__(256, 2) void k_aggr(
        const float* __restrict__ xl,
        const int* __restrict__ src, const int* __restrict__ cidx,
        const int* __restrict__ row_ptr,
        const float* __restrict__ alpha, const float* __restrict__ aself,
        const unsigned* __restrict__ amax,
        const float* __restrict__ bias, int Nn,
        float* __restrict__ out) {
    constexpr int HC = H * 64;
    const int lane = threadIdx.x & 63;
    const int n = (blockIdx.x * blockDim.x + threadIdx.x) >> 6;
    if (n >= Nn) return;
    float mx[H], den[H], acc[H];
#pragma unroll
    for (int h = 0; h < H; ++h) {
        mx[h] = dec_f(amax[(size_t)n * H + h]);
        float p = __expf(aself[(size_t)n * H + h] - mx[h]);
        den[h] = p;
        acc[h] = p * xl[(size_t)n * HC + h * 64 + lane];
    }
    const int beg = row_ptr[n], end = row_ptr[n + 1];
    int i = beg;
    for (; i + 1 < end; i += 2) {
        int ea0 = cidx[i], ea1 = cidx[i + 1];
        int s0 = src[ea0], s1 = src[ea1];
        float xv0[H], xv1[H], p0[H], p1[H];
#pragma unroll
        for (int h = 0; h < H; ++h) {
            xv0[h] = xl[(size_t)s0 * HC + h * 64 + lane];
            xv1[h] = xl[(size_t)s1 * HC + h * 64 + lane];
            p0[h] = __expf(alpha[(size_t)ea0 * H + h] - mx[h]);
            p1[h] = __expf(alpha[(size_t)ea1 * H + h] - mx[h]);
        }
#pragma unroll
        for (int h = 0; h < H; ++h) {
            den[h] += p0[h] + p1[h];
            acc[h] += p0[h] * xv0[h] + p1[h] * xv1[h];
        }
    }
    if (i < end) {
        int e = cidx[i];
        int s = src[e];
#pragma unroll
        for (int h = 0; h < H; ++h) {
            float p = __expf(alpha[(size_t)e * H + h] - mx[h]);
            den[h] += p;
            acc[h] += p * xl[(size_t)s * HC + h * 64 + lane];
        }
    }
#pragma unroll
    for (int h = 0; h < H; ++h) {
        float r = acc[h] / den[h] + bias[h * 64 + lane];
        if (RELU) r = r > 0.f ? r : 0.01f * r;
        out[(size_t)n * HC + h * 64 + lane] = r;
    }
}

// global_add_pool over sorted batch
__global__ void k_pool(const float* __restrict__ h2, const int* __restrict__ batch,
                       int Nn, float* __restrict__ g) {
    const int c = threadIdx.x;  // 0..191
    const int n0 = blockIdx.x * 128;
    if (n0 >= Nn) return;
    const int n1 = (n0 + 128 < Nn) ? n0 + 128 : Nn;
    float s = 0.f;
    int cur = batch[n0];
    for (int n = n0; n < n1; ++n) {
        int b = batch[n];
        if (b != cur) {
            atomicAdd(&g[cur * 192 + c], s);
            s = 0.f;
            cur = b;
        }
        s += h2[(size_t)n * 192 + c];
    }
    atomicAdd(&g[cur * 192 + c], s);
}

__global__ void k_mlp(const float* __restrict__ g,
                      const float* W1, const float* c1, const float* W2, const float* c2,
                      const float* W3, const float* c3, const float* W4, const float* c4,
                      const float* W5, const float* c5, const float* W6, const float* c6,
                      float* __restrict__ out) {
    __shared__ float t0[8 * 192];
    __shared__ float t1[8 * 64];
    __shared__ float t2[8 * 32];
    __shared__ float t3[8 * 16];
    __shared__ float t4[8 * 8];
    const int tid = threadIdx.x;
    for (int i = tid; i < 8 * 192; i += 256) t0[i] = g[i];
    __syncthreads();
    for (int i = tid; i < 8 * 64; i += 256) {
        int r = i >> 6, c = i & 63;
        float s = c1[c];
        for (int k = 0; k < 192; ++k) s += t0[r * 192 + k] * W1[k * 64 + c];
        t1[i] = s > 0.f ? s : 0.01f * s;
    }
    __syncthreads();
    for (int i = tid; i < 8 * 32; i += 256) {
        int r = i >> 5, c = i & 31;
        float s = c2[c];
        for (int k = 0; k < 64; ++k) s += t1[r * 64 + k] * W2[k * 32 + c];
        t2[i] = s > 0.f ? s : 0.01f * s;
    }
    __syncthreads();
    for (int i = tid; i < 8 * 16; i += 256) {
        int r = i >> 4, c = i & 15;
        float s = c3[c];
        for (int k = 0; k < 32; ++k) s += t2[r * 32 + k] * W3[k * 16 + c];
        t3[i] = s > 0.f ? s : 0.01f * s;
    }
    __syncthreads();
    for (int i = tid; i < 8 * 8; i += 256) {
        int r = i >> 3, c = i & 7;
        float s = c4[c];
        for (int k = 0; k < 16; ++k) s += t3[r * 16 + k] * W4[k * 8 + c];
        t4[i] = s > 0.f ? s : 0.01f * s;
    }
    __syncthreads();
    if (tid < 8) {
        float s = c5[0];
        for (int k = 0; k < 8; ++k) s += t4[tid * 8 + k] * W5[k];
        s = s * W6[0] + c6[0];
        out[tid] = s;
    }
}

extern "C" void kernel_launch(void* const* d_in, const int* in_sizes, int n_in,
                              void* d_out, int out_size, void* d_ws, size_t ws_size,
                              hipStream_t stream) {
    const float* x     = (const float*)d_in[0];
    const int*   eidx  = (const int*)d_in[1];
    const float* ea    = (const float*)d_in[2];
    const int*   batch = (const int*)d_in[3];
    const float* Wl1 = (const float*)d_in[4];
    const float* bl1 = (const float*)d_in[5];
    const float* Wr1 = (const float*)d_in[6];
    const float* br1 = (const float*)d_in[7];
    const float* We1 = (const float*)d_in[8];
    const float* att1 = (const float*)d_in[9];
    const float* bias1 = (const float*)d_in[10];
    const float* Wl2 = (const float*)d_in[11];
    const float* bl2 = (const float*)d_in[12];
    const float* Wr2 = (const float*)d_in[13];
    const float* br2 = (const float*)d_in[14];
    const float* We2 = (const float*)d_in[15];
    const float* att2 = (const float*)d_in[16];
    const float* bias2 = (const float*)d_in[17];
    const float* W1 = (const float*)d_in[18];
    const float* c1 = (const float*)d_in[19];
    const float* W2 = (const float*)d_in[20];
    const float* c2 = (const float*)d_in[21];
    const float* W3 = (const float*)d_in[22];
    const float* c3 = (const float*)d_in[23];
    const float* W4 = (const float*)d_in[24];
    const float* c4 = (const float*)d_in[25];
    const float* W5 = (const float*)d_in[26];
    const float* c5 = (const float*)d_in[27];
    const float* W6 = (const float*)d_in[28];
    const float* c6 = (const float*)d_in[29];

    const int N = in_sizes[0] / 128;
    const int E = in_sizes[1] / 2;
    const int* srcs = eidx;
    const int* dsts = eidx + E;

    char* p = (char*)d_ws;
    auto alloc = [&](size_t bytes) -> char* {
        char* r = p;
        p += (bytes + 255) & ~(size_t)255;
        return r;
    };
    int*      deg     = (int*)alloc((size_t)N * 4);
    int*      row_ptr = (int*)alloc((size_t)(N + 1) * 4);
    int*      woff    = (int*)alloc((size_t)N * 4);
    int*      cidx    = (int*)alloc((size_t)E * 4);
    int*      incl    = (int*)alloc((size_t)N * 4);
    int*      bsum    = (int*)alloc(64 * 4);
    float*    easum   = (float*)alloc((size_t)N * 32 * 4);
    float*    xl      = (float*)alloc((size_t)N * 192 * 4);
    float*    xr      = (float*)alloc((size_t)N * 192 * 4);
    float*    h1      = (float*)alloc((size_t)N * 128 * 4);
    float*    h2      = (float*)alloc((size_t)N * 192 * 4);
    float*    alpha   = (float*)alloc((size_t)E * 3 * 4);
    float*    aself   = (float*)alloc((size_t)N * 3 * 4);
    unsigned* amax1   = (unsigned*)alloc((size_t)N * 2 * 4);
    unsigned* amax2   = (unsigned*)alloc((size_t)N * 3 * 4);
    float*    gp      = (float*)alloc(8 * 192 * 4);

    hipMemsetAsync(deg, 0, (size_t)N * 4, stream);
    hipMemsetAsync(easum, 0, (size_t)N * 32 * 4, stream);
    hipMemsetAsync(amax1, 0, (size_t)N * 2 * 4, stream);
    hipMemsetAsync(amax2, 0, (size_t)N * 3 * 4, stream);
    hipMemsetAsync(gp, 0, 8 * 192 * 4, stream);

    // CSR build
    const int nb = (N + 2047) / 2048;
    k_deg<<<(E + 255) / 256, 256, 0, stream>>>(dsts, E, deg);
    k_scan1<<<nb, 256, 0, stream>>>(deg, N, incl, bsum);
    k_scan2<<<1, 64, 0, stream>>>(bsum, nb);
    k_scan3<<<(N + 255) / 256, 256, 0, stream>>>(incl, deg, bsum, N, row_ptr, woff);
    k_scatter<<<(E + 255) / 256, 256, 0, stream>>>(dsts, E, woff, cidx);
    k_easum<<<((E * 32) + 255) / 256, 256, 0, stream>>>(ea, dsts, E, easum);

    const int mt = (N + 63) / 64;             // GEMM row tiles
    const int ablk = ((E + 7) / 8 + 3) / 4;   // k_alpha blocks per head
    const int nblk = (N + 3) / 4;             // node-parallel blocks

    // conv1: H=2, HC=128
    k_xw<128><<<dim3(mt, 2), 256, 0, stream>>>(x, N, Wl1, bl1, Wr1, br1, xl, xr);
    k_selfalpha<2><<<dim3(nblk, 2), 256, 0, stream>>>(xl, xr, easum, deg, We1, att1, N,
                                                      aself, amax1);
    k_alpha<2><<<dim3(ablk, 2), 256, 0, stream>>>(xl, xr, ea, srcs, dsts, E, We1, att1,
                                                  alpha, amax1);
    k_aggr<2, true><<<nblk, 256, 0, stream>>>(xl, srcs, cidx, row_ptr, alpha, aself, amax1,
                                              bias1, N, h1);
    // conv2: H=3, HC=192
    k_xw<192><<<dim3(mt, 3), 256, 0, stream>>>(h1, N, Wl2, bl2, Wr2, br2, xl, xr);
    k_selfalpha<3><<<dim3(nblk, 3), 256, 0, stream>>>(xl, xr, easum, deg, We2, att2, N,
                                                      aself, amax2);
    k_alpha<3><<<dim3(ablk, 3), 256, 0, stream>>>(xl, xr, ea, srcs, dsts, E, We2, att2,
                                                  alpha, amax2);
    k_aggr<3, true><<<nblk, 256, 0, stream>>>(xl, srcs, cidx, row_ptr, alpha, aself, amax2,
                                              bias2, N, h2);

    k_pool<<<(N + 127) / 128, 192, 0, stream>>>(h2, batch, N, gp);
    k_mlp<<<1, 256, 0, stream>>>(gp, W1, c1, W2, c2, W3, c3, W4, c4, W5, c5, W6, c6,
                                 (float*)d_out);
}

// Round 5
// 2105.928 us; speedup vs baseline: 1.3633x; 1.3633x over previous
//
#include <hip/hip_runtime.h>
#include <hip/hip_bf16.h>
#include <math.h>

// ---------------------------------------------------------------------------
// GATv2 x2 + global_add_pool + MLP head, fp32.
// ee = ea@We factored out as LDS-tiled GEMM (EE), so edge kernels are thin
// streaming kernels with tiny register footprints (no We in regs/LDS).
// ---------------------------------------------------------------------------

__device__ __forceinline__ unsigned enc_f(float f) {
    int b = __float_as_int(f);
    unsigned u = (unsigned)b;
    return (b >= 0) ? (u | 0x80000000u) : ~u;
}
__device__ __forceinline__ float dec_f(unsigned u) {
    int b = (u & 0x80000000u) ? (int)(u & 0x7fffffffu) : (int)~u;
    return __int_as_float(b);
}

__global__ void k_deg(const int* __restrict__ dst, int E, int* __restrict__ deg) {
    int e = blockIdx.x * blockDim.x + threadIdx.x;
    if (e < E) atomicAdd(&deg[dst[e]], 1);
}

// ---- multi-block exclusive scan: deg[N] -> row_ptr[N+1], woff[N] ----------
__global__ void k_scan1(const int* __restrict__ deg, int N,
                        int* __restrict__ incl, int* __restrict__ bsum) {
    __shared__ int ws4[4];
    const int tid = threadIdx.x;
    const int lane = tid & 63, w = tid >> 6;
    const int base = blockIdx.x * 2048;
    int v[8];
    int s = 0;
#pragma unroll
    for (int j = 0; j < 8; ++j) {
        int i = base + tid * 8 + j;
        v[j] = (i < N) ? deg[i] : 0;
        s += v[j];
    }
    int ps = s;
#pragma unroll
    for (int off = 1; off < 64; off <<= 1) {
        int t = __shfl_up(ps, off);
        if (lane >= off) ps += t;
    }
    if (lane == 63) ws4[w] = ps;
    __syncthreads();
    int woffs = 0;
#pragma unroll
    for (int k = 0; k < 4; ++k)
        if (k < w) woffs += ws4[k];
    int run = ps - s + woffs;
#pragma unroll
    for (int j = 0; j < 8; ++j) {
        run += v[j];
        int i = base + tid * 8 + j;
        if (i < N) incl[i] = run;
    }
    if (tid == 255) bsum[blockIdx.x] = run;
}

__global__ void k_scan2(int* __restrict__ bsum, int nb) {
    if (threadIdx.x == 0) {
        int c = 0;
        for (int k = 0; k < nb; ++k) { int t = bsum[k]; bsum[k] = c; c += t; }
    }
}

__global__ void k_scan3(const int* __restrict__ incl, const int* __restrict__ deg,
                        const int* __restrict__ boff, int N,
                        int* __restrict__ row_ptr, int* __restrict__ woff) {
    int i = blockIdx.x * blockDim.x + threadIdx.x;
    if (i < N) {
        int v = incl[i] + boff[i >> 11];
        row_ptr[i + 1] = v;
        woff[i] = v - deg[i];
        if (i == 0) row_ptr[0] = 0;
    }
}

__global__ void k_scatter(const int* __restrict__ dst, int E,
                          int* __restrict__ woff, int* __restrict__ cidx) {
    int e = blockIdx.x * blockDim.x + threadIdx.x;
    if (e < E) { int p = atomicAdd(&woff[dst[e]], 1); cidx[p] = e; }
}

__global__ void k_easum(const float* __restrict__ ea, const int* __restrict__ dst,
                        int E, float* __restrict__ easum) {
    int t = blockIdx.x * blockDim.x + threadIdx.x;
    int e = t >> 5, k = t & 31;
    if (e < E) atomicAdd(&easum[(size_t)dst[e] * 32 + k], ea[(size_t)e * 32 + k]);
}

// ---- LDS-tiled GEMM: out{l,r}[n][col] = in[n][:128] . W{l,r}[:, col] + b ----
template <int HC>
__global__ __launch_bounds__(256, 2) void k_xw(
        const float* __restrict__ in, int N,
        const float* __restrict__ Wl, const float* __restrict__ bl,
        const float* __restrict__ Wr, const float* __restrict__ br,
        float* __restrict__ outl, float* __restrict__ outr) {
    __shared__ float Xs[128][68];  // [k][row], +4 pad
    __shared__ float Ws[128][64];  // [k][col]
    const int tid = threadIdx.x;
    const int m0 = blockIdx.x * 64;
    const int cc = blockIdx.y;

#pragma unroll
    for (int t = 0; t < 8; ++t) {
        int idx4 = tid + t * 256;
        int r = idx4 >> 5, k4 = idx4 & 31;
        int n = m0 + r;
        float4 v = make_float4(0.f, 0.f, 0.f, 0.f);
        if (n < N) v = ((const float4*)in)[(size_t)n * 32 + k4];
        Xs[k4 * 4 + 0][r] = v.x;
        Xs[k4 * 4 + 1][r] = v.y;
        Xs[k4 * 4 + 2][r] = v.z;
        Xs[k4 * 4 + 3][r] = v.w;
    }

    const int rm = tid >> 4, rn = tid & 15;
    float acc[4][4];

#pragma unroll
    for (int mat = 0; mat < 2; ++mat) {
        const float* W = mat ? Wr : Wl;
        const float* b = mat ? br : bl;
        float* out = mat ? outr : outl;
        __syncthreads();
#pragma unroll
        for (int i = tid; i < 128 * 64; i += 256) {
            int k = i >> 6, c = i & 63;
            Ws[k][c] = W[(size_t)k * HC + cc * 64 + c];
        }
        __syncthreads();
#pragma unroll
        for (int i = 0; i < 4; ++i)
#pragma unroll
            for (int j = 0; j < 4; ++j) acc[i][j] = 0.f;
#pragma unroll 8
        for (int k = 0; k < 128; ++k) {
            float4 a = *(const float4*)&Xs[k][rm * 4];
            float4 bv = *(const float4*)&Ws[k][rn * 4];
            acc[0][0] += a.x * bv.x; acc[0][1] += a.x * bv.y;
            acc[0][2] += a.x * bv.z; acc[0][3] += a.x * bv.w;
            acc[1][0] += a.y * bv.x; acc[1][1] += a.y * bv.y;
            acc[1][2] += a.y * bv.z; acc[1][3] += a.y * bv.w;
            acc[2][0] += a.z * bv.x; acc[2][1] += a.z * bv.y;
            acc[2][2] += a.z * bv.z; acc[2][3] += a.z * bv.w;
            acc[3][0] += a.w * bv.x; acc[3][1] += a.w * bv.y;
            acc[3][2] += a.w * bv.z; acc[3][3] += a.w * bv.w;
        }
        float4 bb = *(const float4*)&b[cc * 64 + rn * 4];
#pragma unroll
        for (int i = 0; i < 4; ++i) {
            int n = m0 + rm * 4 + i;
            if (n < N) {
                float4 o = make_float4(acc[i][0] + bb.x, acc[i][1] + bb.y,
                                       acc[i][2] + bb.z, acc[i][3] + bb.w);
                *(float4*)&out[(size_t)n * HC + cc * 64 + rn * 4] = o;
            }
        }
    }
}

// ---- EE GEMM: out[m][col] = A[m][:32] . We[:, col]  (A = ea rows or easum) --
template <int HC>
__global__ __launch_bounds__(256, 2) void k_ee(
        const float* __restrict__ A, int M,
        const float* __restrict__ We,
        float* __restrict__ out) {
    __shared__ float As[32][68];  // [k][row], +4 pad
    __shared__ float Ws[32][64];  // [k][col]
    const int tid = threadIdx.x;
    const int m0 = blockIdx.x * 64;
    const int cc = blockIdx.y;

#pragma unroll
    for (int t = 0; t < 2; ++t) {
        int idx4 = tid + t * 256;          // 0..511 : 64 rows x 8 float4
        int r = idx4 >> 3, q = idx4 & 7;
        int n = m0 + r;
        float4 v = make_float4(0.f, 0.f, 0.f, 0.f);
        if (n < M) v = ((const float4*)A)[(size_t)n * 8 + q];
        As[q * 4 + 0][r] = v.x;
        As[q * 4 + 1][r] = v.y;
        As[q * 4 + 2][r] = v.z;
        As[q * 4 + 3][r] = v.w;
    }
#pragma unroll
    for (int i = tid; i < 32 * 64; i += 256) {
        int k = i >> 6, c = i & 63;
        Ws[k][c] = We[(size_t)k * HC + cc * 64 + c];
    }
    __syncthreads();

    const int rm = tid >> 4, rn = tid & 15;
    float acc[4][4];
#pragma unroll
    for (int i = 0; i < 4; ++i)
#pragma unroll
        for (int j = 0; j < 4; ++j) acc[i][j] = 0.f;
#pragma unroll
    for (int k = 0; k < 32; ++k) {
        float4 a = *(const float4*)&As[k][rm * 4];
        float4 bv = *(const float4*)&Ws[k][rn * 4];
        acc[0][0] += a.x * bv.x; acc[0][1] += a.x * bv.y;
        acc[0][2] += a.x * bv.z; acc[0][3] += a.x * bv.w;
        acc[1][0] += a.y * bv.x; acc[1][1] += a.y * bv.y;
        acc[1][2] += a.y * bv.z; acc[1][3] += a.y * bv.w;
        acc[2][0] += a.z * bv.x; acc[2][1] += a.z * bv.y;
        acc[2][2] += a.z * bv.z; acc[2][3] += a.z * bv.w;
        acc[3][0] += a.w * bv.x; acc[3][1] += a.w * bv.y;
        acc[3][2] += a.w * bv.z; acc[3][3] += a.w * bv.w;
    }
#pragma unroll
    for (int i = 0; i < 4; ++i) {
        int n = m0 + rm * 4 + i;
        if (n < M) {
            float4 o = make_float4(acc[i][0], acc[i][1], acc[i][2], acc[i][3]);
            *(float4*)&out[(size_t)n * HC + cc * 64 + rn * 4] = o;
        }
    }
}

// self-loop logits: one wave per node; ee = EEself[n]/max(deg,1) by linearity
template <int H>
__global__ __launch_bounds__(256) void k_selfalpha(
        const float* __restrict__ xl, const float* __restrict__ xr,
        const float* __restrict__ EEself, const int* __restrict__ deg,
        const float* __restrict__ att,
        int Nn, float* __restrict__ aself, unsigned* __restrict__ amax) {
    constexpr int HC = H * 64;
    const int lane = threadIdx.x & 63;
    const int n = (blockIdx.x * blockDim.x + threadIdx.x) >> 6;
    if (n >= Nn) return;
    int dg = deg[n];
    float inv = 1.f / (float)(dg > 0 ? dg : 1);
    float al[H];
#pragma unroll
    for (int h = 0; h < H; ++h) {
        float m = xl[(size_t)n * HC + h * 64 + lane]
                + xr[(size_t)n * HC + h * 64 + lane]
                + EEself[(size_t)n * HC + h * 64 + lane] * inv;
        m = m > 0.f ? m : 0.2f * m;
        al[h] = m * att[h * 64 + lane];
    }
#pragma unroll
    for (int off = 1; off < 64; off <<= 1)
#pragma unroll
        for (int h = 0; h < H; ++h) al[h] += __shfl_xor(al[h], off);
    if (lane == 0) {
#pragma unroll
        for (int h = 0; h < H; ++h) {
            aself[(size_t)n * H + h] = al[h];
            atomicMax(&amax[(size_t)n * H + h], enc_f(al[h]));
        }
    }
}

// edge logits: one wave per edge, EE pre-computed (chunk-local)
template <int H>
__global__ __launch_bounds__(256) void k_alpha(
        const float* __restrict__ xl, const float* __restrict__ xr,
        const float* __restrict__ EE, int ch0, int chlen,
        const int* __restrict__ src, const int* __restrict__ dst,
        const float* __restrict__ att,
        float* __restrict__ alpha, unsigned* __restrict__ amax) {
    constexpr int HC = H * 64;
    const int lane = threadIdx.x & 63;
    const int w = (blockIdx.x * blockDim.x + threadIdx.x) >> 6;
    if (w >= chlen) return;
    const int e = ch0 + w;
    const int s = src[e], d = dst[e];
    float al[H];
#pragma unroll
    for (int h = 0; h < H; ++h) {
        float m = xl[(size_t)s * HC + h * 64 + lane]
                + xr[(size_t)d * HC + h * 64 + lane]
                + EE[(size_t)w * HC + h * 64 + lane];
        m = m > 0.f ? m : 0.2f * m;
        al[h] = m * att[h * 64 + lane];
    }
#pragma unroll
    for (int off = 1; off < 64; off <<= 1)
#pragma unroll
        for (int h = 0; h < H; ++h) al[h] += __shfl_xor(al[h], off);
    if (lane == 0) {
#pragma unroll
        for (int h = 0; h < H; ++h) {
            alpha[(size_t)e * H + h] = al[h];
            atomicMax(&amax[(size_t)d * H + h], enc_f(al[h]));
        }
    }
}

// gather-CSR softmax aggregate: one wave per node, lane = channel
template <int H, bool RELU>
__global__ __launch_bounds__(256, 2) void k_aggr(
        const float* __restrict__ xl,
        const int* __restrict__ src, const int* __restrict__ cidx,
        const int* __restrict__ row_ptr,
        const float* __restrict__ alpha, const float* __restrict__ aself,
        const unsigned* __restrict__ amax,
        const float* __restrict__ bias, int Nn,
        float* __restrict__ out) {
    constexpr int HC = H * 64;
    const int lane = threadIdx.x & 63;
    const int n = (blockIdx.x * blockDim.x + threadIdx.x) >> 6;
    if (n >= Nn) return;
    float mx[H], den[H], acc[H];
#pragma unroll
    for (int h = 0; h < H; ++h) {
        mx[h] = dec_f(amax[(size_t)n * H + h]);
        float p = __expf(aself[(size_t)n * H + h] - mx[h]);
        den[h] = p;
        acc[h] = p * xl[(size_t)n * HC + h * 64 + lane];
    }
    const int beg = row_ptr[n], end = row_ptr[n + 1];
    int i = beg;
    for (; i + 1 < end; i += 2) {
        int ea0 = cidx[i], ea1 = cidx[i + 1];
        int s0 = src[ea0], s1 = src[ea1];
        float xv0[H], xv1[H], p0[H], p1[H];
#pragma unroll
        for (int h = 0; h < H; ++h) {
            xv0[h] = xl[(size_t)s0 * HC + h * 64 + lane];
            xv1[h] = xl[(size_t)s1 * HC + h * 64 + lane];
            p0[h] = __expf(alpha[(size_t)ea0 * H + h] - mx[h]);
            p1[h] = __expf(alpha[(size_t)ea1 * H + h] - mx[h]);
        }
#pragma unroll
        for (int h = 0; h < H; ++h) {
            den[h] += p0[h] + p1[h];
            acc[h] += p0[h] * xv0[h] + p1[h] * xv1[h];
        }
    }
    if (i < end) {
        int e = cidx[i];
        int s = src[e];
#pragma unroll
        for (int h = 0; h < H; ++h) {
            float p = __expf(alpha[(size_t)e * H + h] - mx[h]);
            den[h] += p;
            acc[h] += p * xl[(size_t)s * HC + h * 64 + lane];
        }
    }
#pragma unroll
    for (int h = 0; h < H; ++h) {
        float r = acc[h] / den[h] + bias[h * 64 + lane];
        if (RELU) r = r > 0.f ? r : 0.01f * r;
        out[(size_t)n * HC + h * 64 + lane] = r;
    }
}

// global_add_pool over sorted batch
__global__ void k_pool(const float* __restrict__ h2, const int* __restrict__ batch,
                       int Nn, float* __restrict__ g) {
    const int c = threadIdx.x;  // 0..191
    const int n0 = blockIdx.x * 128;
    if (n0 >= Nn) return;
    const int n1 = (n0 + 128 < Nn) ? n0 + 128 : Nn;
    float s = 0.f;
    int cur = batch[n0];
    for (int n = n0; n < n1; ++n) {
        int b = batch[n];
        if (b != cur) {
            atomicAdd(&g[cur * 192 + c], s);
            s = 0.f;
            cur = b;
        }
        s += h2[(size_t)n * 192 + c];
    }
    atomicAdd(&g[cur * 192 + c], s);
}

__global__ void k_mlp(const float* __restrict__ g,
                      const float* W1, const float* c1, const float* W2, const float* c2,
                      const float* W3, const float* c3, const float* W4, const float* c4,
                      const float* W5, const float* c5, const float* W6, const float* c6,
                      float* __restrict__ out) {
    __shared__ float t0[8 * 192];
    __shared__ float t1[8 * 64];
    __shared__ float t2[8 * 32];
    __shared__ float t3[8 * 16];
    __shared__ float t4[8 * 8];
    const int tid = threadIdx.x;
    for (int i = tid; i < 8 * 192; i += 256) t0[i] = g[i];
    __syncthreads();
    for (int i = tid; i < 8 * 64; i += 256) {
        int r = i >> 6, c = i & 63;
        float s = c1[c];
        for (int k = 0; k < 192; ++k) s += t0[r * 192 + k] * W1[k * 64 + c];
        t1[i] = s > 0.f ? s : 0.01f * s;
    }
    __syncthreads();
    for (int i = tid; i < 8 * 32; i += 256) {
        int r = i >> 5, c = i & 31;
        float s = c2[c];
        for (int k = 0; k < 64; ++k) s += t1[r * 64 + k] * W2[k * 32 + c];
        t2[i] = s > 0.f ? s : 0.01f * s;
    }
    __syncthreads();
    for (int i = tid; i < 8 * 16; i += 256) {
        int r = i >> 4, c = i & 15;
        float s = c3[c];
        for (int k = 0; k < 32; ++k) s += t2[r * 32 + k] * W3[k * 16 + c];
        t3[i] = s > 0.f ? s : 0.01f * s;
    }
    __syncthreads();
    for (int i = tid; i < 8 * 8; i += 256) {
        int r = i >> 3, c = i & 7;
        float s = c4[c];
        for (int k = 0; k < 16; ++k) s += t3[r * 16 + k] * W4[k * 8 + c];
        t4[i] = s > 0.f ? s : 0.01f * s;
    }
    __syncthreads();
    if (tid < 8) {
        float s = c5[0];
        for (int k = 0; k < 8; ++k) s += t4[tid * 8 + k] * W5[k];
        s = s * W6[0] + c6[0];
        out[tid] = s;
    }
}

extern "C" void kernel_launch(void* const* d_in, const int* in_sizes, int n_in,
                              void* d_out, int out_size, void* d_ws, size_t ws_size,
                              hipStream_t stream) {
    const float* x     = (const float*)d_in[0];
    const int*   eidx  = (const int*)d_in[1];
    const float* ea    = (const float*)d_in[2];
    const int*   batch = (const int*)d_in[3];
    const float* Wl1 = (const float*)d_in[4];
    const float* bl1 = (const float*)d_in[5];
    const float* Wr1 = (const float*)d_in[6];
    const float* br1 = (const float*)d_in[7];
    const float* We1 = (const float*)d_in[8];
    const float* att1 = (const float*)d_in[9];
    const float* bias1 = (const float*)d_in[10];
    const float* Wl2 = (const float*)d_in[11];
    const float* bl2 = (const float*)d_in[12];
    const float* Wr2 = (const float*)d_in[13];
    const float* br2 = (const float*)d_in[14];
    const float* We2 = (const float*)d_in[15];
    const float* att2 = (const float*)d_in[16];
    const float* bias2 = (const float*)d_in[17];
    const float* W1 = (const float*)d_in[18];
    const float* c1 = (const float*)d_in[19];
    const float* W2 = (const float*)d_in[20];
    const float* c2 = (const float*)d_in[21];
    const float* W3 = (const float*)d_in[22];
    const float* c3 = (const float*)d_in[23];
    const float* W4 = (const float*)d_in[24];
    const float* c4 = (const float*)d_in[25];
    const float* W5 = (const float*)d_in[26];
    const float* c5 = (const float*)d_in[27];
    const float* W6 = (const float*)d_in[28];
    const float* c6 = (const float*)d_in[29];

    const int N = in_sizes[0] / 128;
    const int E = in_sizes[1] / 2;
    const int* srcs = eidx;
    const int* dsts = eidx + E;

    char* p = (char*)d_ws;
    auto alloc = [&](size_t bytes) -> char* {
        char* r = p;
        p += (bytes + 255) & ~(size_t)255;
        return r;
    };
    int*      deg     = (int*)alloc((size_t)N * 4);
    int*      row_ptr = (int*)alloc((size_t)(N + 1) * 4);
    int*      woff    = (int*)alloc((size_t)N * 4);
    int*      cidx    = (int*)alloc((size_t)E * 4);
    int*      incl    = (int*)alloc((size_t)N * 4);
    int*      bsum    = (int*)alloc(64 * 4);
    float*    easum   = (float*)alloc((size_t)N * 32 * 4);
    float*    EEself  = (float*)alloc((size_t)N * 192 * 4);
    float*    xl      = (float*)alloc((size_t)N * 192 * 4);
    float*    xr      = (float*)alloc((size_t)N * 192 * 4);
    float*    h1      = (float*)alloc((size_t)N * 128 * 4);
    float*    h2      = (float*)alloc((size_t)N * 192 * 4);
    float*    alpha   = (float*)alloc((size_t)E * 3 * 4);
    float*    aself   = (float*)alloc((size_t)N * 3 * 4);
    unsigned* amax1   = (unsigned*)alloc((size_t)N * 2 * 4);
    unsigned* amax2   = (unsigned*)alloc((size_t)N * 3 * 4);
    float*    gp      = (float*)alloc(8 * 192 * 4);

    // EE chunk buffer: remaining workspace
    size_t used = (size_t)(p - (char*)d_ws);
    size_t avail = (ws_size > used) ? ws_size - used : 0;
    long long chk = (long long)(avail / (192 * 4));
    if (chk > E) chk = E;
    chk &= ~63LL;
    if (chk < 4096) chk = 4096;  // last resort; assumes ws is at least modest
    const int chunk = (int)chk;
    float* EEbuf = (float*)p;

    hipMemsetAsync(deg, 0, (size_t)N * 4, stream);
    hipMemsetAsync(easum, 0, (size_t)N * 32 * 4, stream);
    hipMemsetAsync(amax1, 0, (size_t)N * 2 * 4, stream);
    hipMemsetAsync(amax2, 0, (size_t)N * 3 * 4, stream);
    hipMemsetAsync(gp, 0, 8 * 192 * 4, stream);

    // CSR build
    const int nb = (N + 2047) / 2048;
    k_deg<<<(E + 255) / 256, 256, 0, stream>>>(dsts, E, deg);
    k_scan1<<<nb, 256, 0, stream>>>(deg, N, incl, bsum);
    k_scan2<<<1, 64, 0, stream>>>(bsum, nb);
    k_scan3<<<(N + 255) / 256, 256, 0, stream>>>(incl, deg, bsum, N, row_ptr, woff);
    k_scatter<<<(E + 255) / 256, 256, 0, stream>>>(dsts, E, woff, cidx);
    k_easum<<<((E * 32) + 255) / 256, 256, 0, stream>>>(ea, dsts, E, easum);

    const int mt = (N + 63) / 64;   // GEMM row tiles
    const int nblk = (N + 3) / 4;   // node-parallel blocks (1 wave/node)

    // ---------------- conv1: H=2, HC=128 ----------------
    k_xw<128><<<dim3(mt, 2), 256, 0, stream>>>(x, N, Wl1, bl1, Wr1, br1, xl, xr);
    k_ee<128><<<dim3(mt, 2), 256, 0, stream>>>(easum, N, We1, EEself);
    k_selfalpha<2><<<nblk, 256, 0, stream>>>(xl, xr, EEself, deg, att1, N, aself, amax1);
    for (int c0 = 0; c0 < E; c0 += chunk) {
        int cl = (c0 + chunk < E) ? chunk : E - c0;
        k_ee<128><<<dim3((cl + 63) / 64, 2), 256, 0, stream>>>(
            ea + (size_t)c0 * 32, cl, We1, EEbuf);
        k_alpha<2><<<(cl + 3) / 4, 256, 0, stream>>>(
            xl, xr, EEbuf, c0, cl, srcs, dsts, att1, alpha, amax1);
    }
    k_aggr<2, true><<<nblk, 256, 0, stream>>>(xl, srcs, cidx, row_ptr, alpha, aself, amax1,
                                              bias1, N, h1);

    // ---------------- conv2: H=3, HC=192 ----------------
    k_xw<192><<<dim3(mt, 3), 256, 0, stream>>>(h1, N, Wl2, bl2, Wr2, br2, xl, xr);
    k_ee<192><<<dim3(mt, 3), 256, 0, stream>>>(easum, N, We2, EEself);
    k_selfalpha<3><<<nblk, 256, 0, stream>>>(xl, xr, EEself, deg, att2, N, aself, amax2);
    for (int c0 = 0; c0 < E; c0 += chunk) {
        int cl = (c0 + chunk < E) ? chunk : E - c0;
        k_ee<192><<<dim3((cl + 63) / 64, 3), 256, 0, stream>>>(
            ea + (size_t)c0 * 32, cl, We2, EEbuf);
        k_alpha<3><<<(cl + 3) / 4, 256, 0, stream>>>(
            xl, xr, EEbuf, c0, cl, srcs, dsts, att2, alpha, amax2);
    }
    k_aggr<3, true><<<nblk, 256, 0, stream>>>(xl, srcs, cidx, row_ptr, alpha, aself, amax2,
                                              bias2, N, h2);

    k_pool<<<(N + 127) / 128, 192, 0, stream>>>(h2, batch, N, gp);
    k_mlp<<<1, 256, 0, stream>>>(gp, W1, c1, W2, c2, W3, c3, W4, c4, W5, c5, W6, c6,
                                 (float*)d_out);
}

// Round 6
// 1341.214 us; speedup vs baseline: 2.1405x; 1.5702x over previous
//
#include <hip/hip_runtime.h>
#include <hip/hip_bf16.h>
#include <math.h>

// ---------------------------------------------------------------------------
// GATv2 x2 + global_add_pool + MLP head, fp32.
// Edge logits: fused (ea@We)-GEMM + gather + att-dot kernel (EE never hits
// HBM). Self-loop path uses small N-row GEMM (linearity of mean).
// ---------------------------------------------------------------------------

__device__ __forceinline__ unsigned enc_f(float f) {
    int b = __float_as_int(f);
    unsigned u = (unsigned)b;
    return (b >= 0) ? (u | 0x80000000u) : ~u;
}
__device__ __forceinline__ float dec_f(unsigned u) {
    int b = (u & 0x80000000u) ? (int)(u & 0x7fffffffu) : (int)~u;
    return __int_as_float(b);
}

__global__ void k_deg(const int* __restrict__ dst, int E, int* __restrict__ deg) {
    int e = blockIdx.x * blockDim.x + threadIdx.x;
    if (e < E) atomicAdd(&deg[dst[e]], 1);
}

// ---- multi-block exclusive scan: deg[N] -> row_ptr[N+1], woff[N] ----------
__global__ void k_scan1(const int* __restrict__ deg, int N,
                        int* __restrict__ incl, int* __restrict__ bsum) {
    __shared__ int ws4[4];
    const int tid = threadIdx.x;
    const int lane = tid & 63, w = tid >> 6;
    const int base = blockIdx.x * 2048;
    int v[8];
    int s = 0;
#pragma unroll
    for (int j = 0; j < 8; ++j) {
        int i = base + tid * 8 + j;
        v[j] = (i < N) ? deg[i] : 0;
        s += v[j];
    }
    int ps = s;
#pragma unroll
    for (int off = 1; off < 64; off <<= 1) {
        int t = __shfl_up(ps, off);
        if (lane >= off) ps += t;
    }
    if (lane == 63) ws4[w] = ps;
    __syncthreads();
    int woffs = 0;
#pragma unroll
    for (int k = 0; k < 4; ++k)
        if (k < w) woffs += ws4[k];
    int run = ps - s + woffs;
#pragma unroll
    for (int j = 0; j < 8; ++j) {
        run += v[j];
        int i = base + tid * 8 + j;
        if (i < N) incl[i] = run;
    }
    if (tid == 255) bsum[blockIdx.x] = run;
}

__global__ void k_scan2(int* __restrict__ bsum, int nb) {
    if (threadIdx.x == 0) {
        int c = 0;
        for (int k = 0; k < nb; ++k) { int t = bsum[k]; bsum[k] = c; c += t; }
    }
}

__global__ void k_scan3(const int* __restrict__ incl, const int* __restrict__ deg,
                        const int* __restrict__ boff, int N,
                        int* __restrict__ row_ptr, int* __restrict__ woff) {
    int i = blockIdx.x * blockDim.x + threadIdx.x;
    if (i < N) {
        int v = incl[i] + boff[i >> 11];
        row_ptr[i + 1] = v;
        woff[i] = v - deg[i];
        if (i == 0) row_ptr[0] = 0;
    }
}

__global__ void k_scatter(const int* __restrict__ dst, int E,
                          int* __restrict__ woff, int* __restrict__ cidx) {
    int e = blockIdx.x * blockDim.x + threadIdx.x;
    if (e < E) { int p = atomicAdd(&woff[dst[e]], 1); cidx[p] = e; }
}

__global__ void k_easum(const float* __restrict__ ea, const int* __restrict__ dst,
                        int E, float* __restrict__ easum) {
    int t = blockIdx.x * blockDim.x + threadIdx.x;
    int e = t >> 5, k = t & 31;
    if (e < E) atomicAdd(&easum[(size_t)dst[e] * 32 + k], ea[(size_t)e * 32 + k]);
}

// ---- LDS-tiled GEMM: out{l,r}[n][col] = in[n][:128] . W{l,r}[:, col] + b ----
template <int HC>
__global__ __launch_bounds__(256, 2) void k_xw(
        const float* __restrict__ in, int N,
        const float* __restrict__ Wl, const float* __restrict__ bl,
        const float* __restrict__ Wr, const float* __restrict__ br,
        float* __restrict__ outl, float* __restrict__ outr) {
    __shared__ float Xs[128][68];  // [k][row], +4 pad
    __shared__ float Ws[128][64];  // [k][col]
    const int tid = threadIdx.x;
    const int m0 = blockIdx.x * 64;
    const int cc = blockIdx.y;

#pragma unroll
    for (int t = 0; t < 8; ++t) {
        int idx4 = tid + t * 256;
        int r = idx4 >> 5, k4 = idx4 & 31;
        int n = m0 + r;
        float4 v = make_float4(0.f, 0.f, 0.f, 0.f);
        if (n < N) v = ((const float4*)in)[(size_t)n * 32 + k4];
        Xs[k4 * 4 + 0][r] = v.x;
        Xs[k4 * 4 + 1][r] = v.y;
        Xs[k4 * 4 + 2][r] = v.z;
        Xs[k4 * 4 + 3][r] = v.w;
    }

    const int rm = tid >> 4, rn = tid & 15;
    float acc[4][4];

#pragma unroll
    for (int mat = 0; mat < 2; ++mat) {
        const float* W = mat ? Wr : Wl;
        const float* b = mat ? br : bl;
        float* out = mat ? outr : outl;
        __syncthreads();
#pragma unroll
        for (int i = tid; i < 128 * 64; i += 256) {
            int k = i >> 6, c = i & 63;
            Ws[k][c] = W[(size_t)k * HC + cc * 64 + c];
        }
        __syncthreads();
#pragma unroll
        for (int i = 0; i < 4; ++i)
#pragma unroll
            for (int j = 0; j < 4; ++j) acc[i][j] = 0.f;
#pragma unroll 8
        for (int k = 0; k < 128; ++k) {
            float4 a = *(const float4*)&Xs[k][rm * 4];
            float4 bv = *(const float4*)&Ws[k][rn * 4];
            acc[0][0] += a.x * bv.x; acc[0][1] += a.x * bv.y;
            acc[0][2] += a.x * bv.z; acc[0][3] += a.x * bv.w;
            acc[1][0] += a.y * bv.x; acc[1][1] += a.y * bv.y;
            acc[1][2] += a.y * bv.z; acc[1][3] += a.y * bv.w;
            acc[2][0] += a.z * bv.x; acc[2][1] += a.z * bv.y;
            acc[2][2] += a.z * bv.z; acc[2][3] += a.z * bv.w;
            acc[3][0] += a.w * bv.x; acc[3][1] += a.w * bv.y;
            acc[3][2] += a.w * bv.z; acc[3][3] += a.w * bv.w;
        }
        float4 bb = *(const float4*)&b[cc * 64 + rn * 4];
#pragma unroll
        for (int i = 0; i < 4; ++i) {
            int n = m0 + rm * 4 + i;
            if (n < N) {
                float4 o = make_float4(acc[i][0] + bb.x, acc[i][1] + bb.y,
                                       acc[i][2] + bb.z, acc[i][3] + bb.w);
                *(float4*)&out[(size_t)n * HC + cc * 64 + rn * 4] = o;
            }
        }
    }
}

// ---- EE GEMM (self-loop path): out[m][col] = A[m][:32] . We[:, col] --------
template <int HC>
__global__ __launch_bounds__(256, 2) void k_ee(
        const float* __restrict__ A, int M,
        const float* __restrict__ We,
        float* __restrict__ out) {
    __shared__ float As[32][68];
    __shared__ float Ws[32][64];
    const int tid = threadIdx.x;
    const int m0 = blockIdx.x * 64;
    const int cc = blockIdx.y;

#pragma unroll
    for (int t = 0; t < 2; ++t) {
        int idx4 = tid + t * 256;
        int r = idx4 >> 3, q = idx4 & 7;
        int n = m0 + r;
        float4 v = make_float4(0.f, 0.f, 0.f, 0.f);
        if (n < M) v = ((const float4*)A)[(size_t)n * 8 + q];
        As[q * 4 + 0][r] = v.x;
        As[q * 4 + 1][r] = v.y;
        As[q * 4 + 2][r] = v.z;
        As[q * 4 + 3][r] = v.w;
    }
#pragma unroll
    for (int i = tid; i < 32 * 64; i += 256) {
        int k = i >> 6, c = i & 63;
        Ws[k][c] = We[(size_t)k * HC + cc * 64 + c];
    }
    __syncthreads();

    const int rm = tid >> 4, rn = tid & 15;
    float acc[4][4];
#pragma unroll
    for (int i = 0; i < 4; ++i)
#pragma unroll
        for (int j = 0; j < 4; ++j) acc[i][j] = 0.f;
#pragma unroll
    for (int k = 0; k < 32; ++k) {
        float4 a = *(const float4*)&As[k][rm * 4];
        float4 bv = *(const float4*)&Ws[k][rn * 4];
        acc[0][0] += a.x * bv.x; acc[0][1] += a.x * bv.y;
        acc[0][2] += a.x * bv.z; acc[0][3] += a.x * bv.w;
        acc[1][0] += a.y * bv.x; acc[1][1] += a.y * bv.y;
        acc[1][2] += a.y * bv.z; acc[1][3] += a.y * bv.w;
        acc[2][0] += a.z * bv.x; acc[2][1] += a.z * bv.y;
        acc[2][2] += a.z * bv.z; acc[2][3] += a.z * bv.w;
        acc[3][0] += a.w * bv.x; acc[3][1] += a.w * bv.y;
        acc[3][2] += a.w * bv.z; acc[3][3] += a.w * bv.w;
    }
#pragma unroll
    for (int i = 0; i < 4; ++i) {
        int n = m0 + rm * 4 + i;
        if (n < M) {
            float4 o = make_float4(acc[i][0], acc[i][1], acc[i][2], acc[i][3]);
            *(float4*)&out[(size_t)n * HC + cc * 64 + rn * 4] = o;
        }
    }
}

// ---- fused edge logits: (ea@We) GEMM in LDS + gather + att-dot + reduce ----
// block = 64 edges; loop over heads (cc = one 64-col head chunk).
template <int H>
__global__ __launch_bounds__(256, 2) void k_fused(
        const float* __restrict__ xl, const float* __restrict__ xr,
        const float* __restrict__ ea,
        const int* __restrict__ src, const int* __restrict__ dst, int E,
        const float* __restrict__ We, const float* __restrict__ att,
        float* __restrict__ alpha, unsigned* __restrict__ amax) {
    constexpr int HC = H * 64;
    __shared__ float As[32][68];  // ea tile, [k][edge-row]
    __shared__ float Ws[32][64];  // We head chunk, [k][col]
    __shared__ int Ss[64], Ds[64];
    const int tid = threadIdx.x;
    const int m0 = blockIdx.x * 64;

    if (tid < 64) {
        int e = m0 + tid;
        Ss[tid] = (e < E) ? src[e] : 0;
        Ds[tid] = (e < E) ? dst[e] : 0;
    }
#pragma unroll
    for (int t = 0; t < 2; ++t) {
        int idx4 = tid + t * 256;
        int r = idx4 >> 3, q = idx4 & 7;
        int e = m0 + r;
        float4 v = make_float4(0.f, 0.f, 0.f, 0.f);
        if (e < E) v = ((const float4*)ea)[(size_t)e * 8 + q];
        As[q * 4 + 0][r] = v.x;
        As[q * 4 + 1][r] = v.y;
        As[q * 4 + 2][r] = v.z;
        As[q * 4 + 3][r] = v.w;
    }

    const int rm = tid >> 4, rn = tid & 15;

#pragma unroll
    for (int cc = 0; cc < H; ++cc) {
        __syncthreads();  // As/Ss ready (cc=0); prev chunk reads done (cc>0)
#pragma unroll
        for (int i = tid; i < 32 * 64; i += 256) {
            int k = i >> 6, c = i & 63;
            Ws[k][c] = We[(size_t)k * HC + cc * 64 + c];
        }
        __syncthreads();
        float acc[4][4];
#pragma unroll
        for (int i = 0; i < 4; ++i)
#pragma unroll
            for (int j = 0; j < 4; ++j) acc[i][j] = 0.f;
#pragma unroll
        for (int k = 0; k < 32; ++k) {
            float4 a = *(const float4*)&As[k][rm * 4];
            float4 bv = *(const float4*)&Ws[k][rn * 4];
            acc[0][0] += a.x * bv.x; acc[0][1] += a.x * bv.y;
            acc[0][2] += a.x * bv.z; acc[0][3] += a.x * bv.w;
            acc[1][0] += a.y * bv.x; acc[1][1] += a.y * bv.y;
            acc[1][2] += a.y * bv.z; acc[1][3] += a.y * bv.w;
            acc[2][0] += a.z * bv.x; acc[2][1] += a.z * bv.y;
            acc[2][2] += a.z * bv.z; acc[2][3] += a.z * bv.w;
            acc[3][0] += a.w * bv.x; acc[3][1] += a.w * bv.y;
            acc[3][2] += a.w * bv.z; acc[3][3] += a.w * bv.w;
        }
        // consume: gather xl/xr, leaky-relu, att-dot, per-edge partial
        float4 at4 = *(const float4*)&att[cc * 64 + rn * 4];
        float part[4];
#pragma unroll
        for (int i = 0; i < 4; ++i) {
            int s = Ss[rm * 4 + i], d = Ds[rm * 4 + i];
            float4 xa = *(const float4*)&xl[(size_t)s * HC + cc * 64 + rn * 4];
            float4 xb = *(const float4*)&xr[(size_t)d * HC + cc * 64 + rn * 4];
            float m0v = xa.x + xb.x + acc[i][0];
            float m1v = xa.y + xb.y + acc[i][1];
            float m2v = xa.z + xb.z + acc[i][2];
            float m3v = xa.w + xb.w + acc[i][3];
            m0v = m0v > 0.f ? m0v : 0.2f * m0v;
            m1v = m1v > 0.f ? m1v : 0.2f * m1v;
            m2v = m2v > 0.f ? m2v : 0.2f * m2v;
            m3v = m3v > 0.f ? m3v : 0.2f * m3v;
            part[i] = m0v * at4.x + m1v * at4.y + m2v * at4.z + m3v * at4.w;
        }
        // reduce across the 16 rn-lanes (within-wave 16-lane groups)
#pragma unroll
        for (int off = 1; off < 16; off <<= 1)
#pragma unroll
            for (int i = 0; i < 4; ++i) part[i] += __shfl_xor(part[i], off);
        if (rn == 0) {
#pragma unroll
            for (int i = 0; i < 4; ++i) {
                int e = m0 + rm * 4 + i;
                if (e < E) {
                    alpha[(size_t)e * H + cc] = part[i];
                    atomicMax(&amax[(size_t)Ds[rm * 4 + i] * H + cc], enc_f(part[i]));
                }
            }
        }
    }
}

// self-loop logits: one wave per node; ee = EEself[n]/max(deg,1) by linearity
template <int H>
__global__ __launch_bounds__(256) void k_selfalpha(
        const float* __restrict__ xl, const float* __restrict__ xr,
        const float* __restrict__ EEself, const int* __restrict__ deg,
        const float* __restrict__ att,
        int Nn, float* __restrict__ aself, unsigned* __restrict__ amax) {
    constexpr int HC = H * 64;
    const int lane = threadIdx.x & 63;
    const int n = (blockIdx.x * blockDim.x + threadIdx.x) >> 6;
    if (n >= Nn) return;
    int dg = deg[n];
    float inv = 1.f / (float)(dg > 0 ? dg : 1);
    float al[H];
#pragma unroll
    for (int h = 0; h < H; ++h) {
        float m = xl[(size_t)n * HC + h * 64 + lane]
                + xr[(size_t)n * HC + h * 64 + lane]
                + EEself[(size_t)n * HC + h * 64 + lane] * inv;
        m = m > 0.f ? m : 0.2f * m;
        al[h] = m * att[h * 64 + lane];
    }
#pragma unroll
    for (int off = 1; off < 64; off <<= 1)
#pragma unroll
        for (int h = 0; h < H; ++h) al[h] += __shfl_xor(al[h], off);
    if (lane == 0) {
#pragma unroll
        for (int h = 0; h < H; ++h) {
            aself[(size_t)n * H + h] = al[h];
            atomicMax(&amax[(size_t)n * H + h], enc_f(al[h]));
        }
    }
}

// gather-CSR softmax aggregate: one wave per node, lane = channel
template <int H, bool RELU>
__global__ __launch_bounds__(256, 2) void k_aggr(
        const float* __restrict__ xl,
        const int* __restrict__ src, const int* __restrict__ cidx,
        const int* __restrict__ row_ptr,
        const float* __restrict__ alpha, const float* __restrict__ aself,
        const unsigned* __restrict__ amax,
        const float* __restrict__ bias, int Nn,
        float* __restrict__ out) {
    constexpr int HC = H * 64;
    const int lane = threadIdx.x & 63;
    const int n = (blockIdx.x * blockDim.x + threadIdx.x) >> 6;
    if (n >= Nn) return;
    float mx[H], den[H], acc[H];
#pragma unroll
    for (int h = 0; h < H; ++h) {
        mx[h] = dec_f(amax[(size_t)n * H + h]);
        float p = __expf(aself[(size_t)n * H + h] - mx[h]);
        den[h] = p;
        acc[h] = p * xl[(size_t)n * HC + h * 64 + lane];
    }
    const int beg = row_ptr[n], end = row_ptr[n + 1];
    int i = beg;
    for (; i + 1 < end; i += 2) {
        int ea0 = cidx[i], ea1 = cidx[i + 1];
        int s0 = src[ea0], s1 = src[ea1];
        float xv0[H], xv1[H], p0[H], p1[H];
#pragma unroll
        for (int h = 0; h < H; ++h) {
            xv0[h] = xl[(size_t)s0 * HC + h * 64 + lane];
            xv1[h] = xl[(size_t)s1 * HC + h * 64 + lane];
            p0[h] = __expf(alpha[(size_t)ea0 * H + h] - mx[h]);
            p1[h] = __expf(alpha[(size_t)ea1 * H + h] - mx[h]);
        }
#pragma unroll
        for (int h = 0; h < H; ++h) {
            den[h] += p0[h] + p1[h];
            acc[h] += p0[h] * xv0[h] + p1[h] * xv1[h];
        }
    }
    if (i < end) {
        int e = cidx[i];
        int s = src[e];
#pragma unroll
        for (int h = 0; h < H; ++h) {
            float p = __expf(alpha[(size_t)e * H + h] - mx[h]);
            den[h] += p;
            acc[h] += p * xl[(size_t)s * HC + h * 64 + lane];
        }
    }
#pragma unroll
    for (int h = 0; h < H; ++h) {
        float r = acc[h] / den[h] + bias[h * 64 + lane];
        if (RELU) r = r > 0.f ? r : 0.01f * r;
        out[(size_t)n * HC + h * 64 + lane] = r;
    }
}

// global_add_pool over sorted batch
__global__ void k_pool(const float* __restrict__ h2, const int* __restrict__ batch,
                       int Nn, float* __restrict__ g) {
    const int c = threadIdx.x;  // 0..191
    const int n0 = blockIdx.x * 128;
    if (n0 >= Nn) return;
    const int n1 = (n0 + 128 < Nn) ? n0 + 128 : Nn;
    float s = 0.f;
    int cur = batch[n0];
    for (int n = n0; n < n1; ++n) {
        int b = batch[n];
        if (b != cur) {
            atomicAdd(&g[cur * 192 + c], s);
            s = 0.f;
            cur = b;
        }
        s += h2[(size_t)n * 192 + c];
    }
    atomicAdd(&g[cur * 192 + c], s);
}

__global__ void k_mlp(const float* __restrict__ g,
                      const float* W1, const float* c1, const float* W2, const float* c2,
                      const float* W3, const float* c3, const float* W4, const float* c4,
                      const float* W5, const float* c5, const float* W6, const float* c6,
                      float* __restrict__ out) {
    __shared__ float t0[8 * 192];
    __shared__ float t1[8 * 64];
    __shared__ float t2[8 * 32];
    __shared__ float t3[8 * 16];
    __shared__ float t4[8 * 8];
    const int tid = threadIdx.x;
    for (int i = tid; i < 8 * 192; i += 256) t0[i] = g[i];
    __syncthreads();
    for (int i = tid; i < 8 * 64; i += 256) {
        int r = i >> 6, c = i & 63;
        float s = c1[c];
        for (int k = 0; k < 192; ++k) s += t0[r * 192 + k] * W1[k * 64 + c];
        t1[i] = s > 0.f ? s : 0.01f * s;
    }
    __syncthreads();
    for (int i = tid; i < 8 * 32; i += 256) {
        int r = i >> 5, c = i & 31;
        float s = c2[c];
        for (int k = 0; k < 64; ++k) s += t1[r * 64 + k] * W2[k * 32 + c];
        t2[i] = s > 0.f ? s : 0.01f * s;
    }
    __syncthreads();
    for (int i = tid; i < 8 * 16; i += 256) {
        int r = i >> 4, c = i & 15;
        float s = c3[c];
        for (int k = 0; k < 32; ++k) s += t2[r * 32 + k] * W3[k * 16 + c];
        t3[i] = s > 0.f ? s : 0.01f * s;
    }
    __syncthreads();
    for (int i = tid; i < 8 * 8; i += 256) {
        int r = i >> 3, c = i & 7;
        float s = c4[c];
        for (int k = 0; k < 16; ++k) s += t3[r * 16 + k] * W4[k * 8 + c];
        t4[i] = s > 0.f ? s : 0.01f * s;
    }
    __syncthreads();
    if (tid < 8) {
        float s = c5[0];
        for (int k = 0; k < 8; ++k) s += t4[tid * 8 + k] * W5[k];
        s = s * W6[0] + c6[0];
        out[tid] = s;
    }
}

extern "C" void kernel_launch(void* const* d_in, const int* in_sizes, int n_in,
                              void* d_out, int out_size, void* d_ws, size_t ws_size,
                              hipStream_t stream) {
    const float* x     = (const float*)d_in[0];
    const int*   eidx  = (const int*)d_in[1];
    const float* ea    = (const float*)d_in[2];
    const int*   batch = (const int*)d_in[3];
    const float* Wl1 = (const float*)d_in[4];
    const float* bl1 = (const float*)d_in[5];
    const float* Wr1 = (const float*)d_in[6];
    const float* br1 = (const float*)d_in[7];
    const float* We1 = (const float*)d_in[8];
    const float* att1 = (const float*)d_in[9];
    const float* bias1 = (const float*)d_in[10];
    const float* Wl2 = (const float*)d_in[11];
    const float* bl2 = (const float*)d_in[12];
    const float* Wr2 = (const float*)d_in[13];
    const float* br2 = (const float*)d_in[14];
    const float* We2 = (const float*)d_in[15];
    const float* att2 = (const float*)d_in[16];
    const float* bias2 = (const float*)d_in[17];
    const float* W1 = (const float*)d_in[18];
    const float* c1 = (const float*)d_in[19];
    const float* W2 = (const float*)d_in[20];
    const float* c2 = (const float*)d_in[21];
    const float* W3 = (const float*)d_in[22];
    const float* c3 = (const float*)d_in[23];
    const float* W4 = (const float*)d_in[24];
    const float* c4 = (const float*)d_in[25];
    const float* W5 = (const float*)d_in[26];
    const float* c5 = (const float*)d_in[27];
    const float* W6 = (const float*)d_in[28];
    const float* c6 = (const float*)d_in[29];

    const int N = in_sizes[0] / 128;
    const int E = in_sizes[1] / 2;
    const int* srcs = eidx;
    const int* dsts = eidx + E;

    char* p = (char*)d_ws;
    auto alloc = [&](size_t bytes) -> char* {
        char* r = p;
        p += (bytes + 255) & ~(size_t)255;
        return r;
    };
    int*      deg     = (int*)alloc((size_t)N * 4);
    int*      row_ptr = (int*)alloc((size_t)(N + 1) * 4);
    int*      woff    = (int*)alloc((size_t)N * 4);
    int*      cidx    = (int*)alloc((size_t)E * 4);
    int*      incl    = (int*)alloc((size_t)N * 4);
    int*      bsum    = (int*)alloc(64 * 4);
    float*    easum   = (float*)alloc((size_t)N * 32 * 4);
    float*    EEself  = (float*)alloc((size_t)N * 192 * 4);
    float*    xl      = (float*)alloc((size_t)N * 192 * 4);
    float*    xr      = (float*)alloc((size_t)N * 192 * 4);
    float*    h1      = (float*)alloc((size_t)N * 128 * 4);
    float*    h2      = (float*)alloc((size_t)N * 192 * 4);
    float*    alpha   = (float*)alloc((size_t)E * 3 * 4);
    float*    aself   = (float*)alloc((size_t)N * 3 * 4);
    unsigned* amax1   = (unsigned*)alloc((size_t)N * 2 * 4);
    unsigned* amax2   = (unsigned*)alloc((size_t)N * 3 * 4);
    float*    gp      = (float*)alloc(8 * 192 * 4);

    hipMemsetAsync(deg, 0, (size_t)N * 4, stream);
    hipMemsetAsync(easum, 0, (size_t)N * 32 * 4, stream);
    hipMemsetAsync(amax1, 0, (size_t)N * 2 * 4, stream);
    hipMemsetAsync(amax2, 0, (size_t)N * 3 * 4, stream);
    hipMemsetAsync(gp, 0, 8 * 192 * 4, stream);

    // CSR build
    const int nb = (N + 2047) / 2048;
    k_deg<<<(E + 255) / 256, 256, 0, stream>>>(dsts, E, deg);
    k_scan1<<<nb, 256, 0, stream>>>(deg, N, incl, bsum);
    k_scan2<<<1, 64, 0, stream>>>(bsum, nb);
    k_scan3<<<(N + 255) / 256, 256, 0, stream>>>(incl, deg, bsum, N, row_ptr, woff);
    k_scatter<<<(E + 255) / 256, 256, 0, stream>>>(dsts, E, woff, cidx);
    k_easum<<<((E * 32) + 255) / 256, 256, 0, stream>>>(ea, dsts, E, easum);

    const int mt = (N + 63) / 64;   // GEMM row tiles
    const int et = (E + 63) / 64;   // fused edge tiles
    const int nblk = (N + 3) / 4;   // node-parallel blocks (1 wave/node)

    // ---------------- conv1: H=2, HC=128 ----------------
    k_xw<128><<<dim3(mt, 2), 256, 0, stream>>>(x, N, Wl1, bl1, Wr1, br1, xl, xr);
    k_ee<128><<<dim3(mt, 2), 256, 0, stream>>>(easum, N, We1, EEself);
    k_selfalpha<2><<<nblk, 256, 0, stream>>>(xl, xr, EEself, deg, att1, N, aself, amax1);
    k_fused<2><<<et, 256, 0, stream>>>(xl, xr, ea, srcs, dsts, E, We1, att1, alpha, amax1);
    k_aggr<2, true><<<nblk, 256, 0, stream>>>(xl, srcs, cidx, row_ptr, alpha, aself, amax1,
                                              bias1, N, h1);

    // ---------------- conv2: H=3, HC=192 ----------------
    k_xw<192><<<dim3(mt, 3), 256, 0, stream>>>(h1, N, Wl2, bl2, Wr2, br2, xl, xr);
    k_ee<192><<<dim3(mt, 3), 256, 0, stream>>>(easum, N, We2, EEself);
    k_selfalpha<3><<<nblk, 256, 0, stream>>>(xl, xr, EEself, deg, att2, N, aself, amax2);
    k_fused<3><<<et, 256, 0, stream>>>(xl, xr, ea, srcs, dsts, E, We2, att2, alpha, amax2);
    k_aggr<3, true><<<nblk, 256, 0, stream>>>(xl, srcs, cidx, row_ptr, alpha, aself, amax2,
                                              bias2, N, h2);

    k_pool<<<(N + 127) / 128, 192, 0, stream>>>(h2, batch, N, gp);
    k_mlp<<<1, 256, 0, stream>>>(gp, W1, c1, W2, c2, W3, c3, W4, c4, W5, c5, W6, c6,
                                 (float*)d_out);
}

// Round 7
// 1247.354 us; speedup vs baseline: 2.3016x; 1.0752x over previous
//
#include <hip/hip_runtime.h>
#include <hip/hip_bf16.h>
#include <math.h>

// ---------------------------------------------------------------------------
// GATv2 x2 + global_add_pool + MLP head, fp32.
// CSR-ordered fused edge kernel (ea@We GEMM in LDS + gather + att-dot),
// contiguous alpha, online-softmax aggregation (no atomics in hot path).
// ---------------------------------------------------------------------------

__global__ void k_deg(const int* __restrict__ dst, int E, int* __restrict__ deg) {
    int e = blockIdx.x * blockDim.x + threadIdx.x;
    if (e < E) atomicAdd(&deg[dst[e]], 1);
}

// ---- multi-block exclusive scan: deg[N] -> row_ptr[N+1], woff[N] ----------
__global__ void k_scan1(const int* __restrict__ deg, int N,
                        int* __restrict__ incl, int* __restrict__ bsum) {
    __shared__ int ws4[4];
    const int tid = threadIdx.x;
    const int lane = tid & 63, w = tid >> 6;
    const int base = blockIdx.x * 2048;
    int v[8];
    int s = 0;
#pragma unroll
    for (int j = 0; j < 8; ++j) {
        int i = base + tid * 8 + j;
        v[j] = (i < N) ? deg[i] : 0;
        s += v[j];
    }
    int ps = s;
#pragma unroll
    for (int off = 1; off < 64; off <<= 1) {
        int t = __shfl_up(ps, off);
        if (lane >= off) ps += t;
    }
    if (lane == 63) ws4[w] = ps;
    __syncthreads();
    int woffs = 0;
#pragma unroll
    for (int k = 0; k < 4; ++k)
        if (k < w) woffs += ws4[k];
    int run = ps - s + woffs;
#pragma unroll
    for (int j = 0; j < 8; ++j) {
        run += v[j];
        int i = base + tid * 8 + j;
        if (i < N) incl[i] = run;
    }
    if (tid == 255) bsum[blockIdx.x] = run;
}

__global__ void k_scan2(int* __restrict__ bsum, int nb) {
    if (threadIdx.x == 0) {
        int c = 0;
        for (int k = 0; k < nb; ++k) { int t = bsum[k]; bsum[k] = c; c += t; }
    }
}

__global__ void k_scan3(const int* __restrict__ incl, const int* __restrict__ deg,
                        const int* __restrict__ boff, int N,
                        int* __restrict__ row_ptr, int* __restrict__ woff) {
    int i = blockIdx.x * blockDim.x + threadIdx.x;
    if (i < N) {
        int v = incl[i] + boff[i >> 11];
        row_ptr[i + 1] = v;
        woff[i] = v - deg[i];
        if (i == 0) row_ptr[0] = 0;
    }
}

// scatter edges into CSR order; also materialize src/dst in CSR order
__global__ void k_scatter(const int* __restrict__ src, const int* __restrict__ dst,
                          int E, int* __restrict__ woff, int* __restrict__ cidx,
                          int* __restrict__ s_csr, int* __restrict__ d_csr) {
    int e = blockIdx.x * blockDim.x + threadIdx.x;
    if (e < E) {
        int d = dst[e];
        int p = atomicAdd(&woff[d], 1);
        cidx[p] = e;
        s_csr[p] = src[e];
        d_csr[p] = d;
    }
}

// segmented sum of edge attrs per dst (CSR order): one wave per node, lane<32
__global__ void k_easeg(const float* __restrict__ ea, const int* __restrict__ cidx,
                        const int* __restrict__ row_ptr, int N,
                        float* __restrict__ easum) {
    const int w = (blockIdx.x * blockDim.x + threadIdx.x) >> 6;
    const int lane = threadIdx.x & 63;
    if (w >= N || lane >= 32) return;
    const int beg = row_ptr[w], end = row_ptr[w + 1];
    float s = 0.f;
    for (int i = beg; i < end; ++i) {
        int e = cidx[i];
        s += ea[(size_t)e * 32 + lane];
    }
    easum[(size_t)w * 32 + lane] = s;
}

// ---- LDS-tiled GEMM: out{l,r}[n][col] = in[n][:128] . W{l,r}[:, col] + b ----
template <int HC>
__global__ __launch_bounds__(256, 2) void k_xw(
        const float* __restrict__ in, int N,
        const float* __restrict__ Wl, const float* __restrict__ bl,
        const float* __restrict__ Wr, const float* __restrict__ br,
        float* __restrict__ outl, float* __restrict__ outr) {
    __shared__ float Xs[128][68];  // [k][row], +4 pad
    __shared__ float Ws[128][64];  // [k][col]
    const int tid = threadIdx.x;
    const int m0 = blockIdx.x * 64;
    const int cc = blockIdx.y;

#pragma unroll
    for (int t = 0; t < 8; ++t) {
        int idx4 = tid + t * 256;
        int r = idx4 >> 5, k4 = idx4 & 31;
        int n = m0 + r;
        float4 v = make_float4(0.f, 0.f, 0.f, 0.f);
        if (n < N) v = ((const float4*)in)[(size_t)n * 32 + k4];
        Xs[k4 * 4 + 0][r] = v.x;
        Xs[k4 * 4 + 1][r] = v.y;
        Xs[k4 * 4 + 2][r] = v.z;
        Xs[k4 * 4 + 3][r] = v.w;
    }

    const int rm = tid >> 4, rn = tid & 15;
    float acc[4][4];

#pragma unroll
    for (int mat = 0; mat < 2; ++mat) {
        const float* W = mat ? Wr : Wl;
        const float* b = mat ? br : bl;
        float* out = mat ? outr : outl;
        __syncthreads();
#pragma unroll
        for (int i = tid; i < 128 * 64; i += 256) {
            int k = i >> 6, c = i & 63;
            Ws[k][c] = W[(size_t)k * HC + cc * 64 + c];
        }
        __syncthreads();
#pragma unroll
        for (int i = 0; i < 4; ++i)
#pragma unroll
            for (int j = 0; j < 4; ++j) acc[i][j] = 0.f;
#pragma unroll 8
        for (int k = 0; k < 128; ++k) {
            float4 a = *(const float4*)&Xs[k][rm * 4];
            float4 bv = *(const float4*)&Ws[k][rn * 4];
            acc[0][0] += a.x * bv.x; acc[0][1] += a.x * bv.y;
            acc[0][2] += a.x * bv.z; acc[0][3] += a.x * bv.w;
            acc[1][0] += a.y * bv.x; acc[1][1] += a.y * bv.y;
            acc[1][2] += a.y * bv.z; acc[1][3] += a.y * bv.w;
            acc[2][0] += a.z * bv.x; acc[2][1] += a.z * bv.y;
            acc[2][2] += a.z * bv.z; acc[2][3] += a.z * bv.w;
            acc[3][0] += a.w * bv.x; acc[3][1] += a.w * bv.y;
            acc[3][2] += a.w * bv.z; acc[3][3] += a.w * bv.w;
        }
        float4 bb = *(const float4*)&b[cc * 64 + rn * 4];
#pragma unroll
        for (int i = 0; i < 4; ++i) {
            int n = m0 + rm * 4 + i;
            if (n < N) {
                float4 o = make_float4(acc[i][0] + bb.x, acc[i][1] + bb.y,
                                       acc[i][2] + bb.z, acc[i][3] + bb.w);
                *(float4*)&out[(size_t)n * HC + cc * 64 + rn * 4] = o;
            }
        }
    }
}

// ---- EE GEMM (self-loop path): out[m][col] = A[m][:32] . We[:, col] --------
template <int HC>
__global__ __launch_bounds__(256, 2) void k_ee(
        const float* __restrict__ A, int M,
        const float* __restrict__ We,
        float* __restrict__ out) {
    __shared__ float As[32][68];
    __shared__ float Ws[32][64];
    const int tid = threadIdx.x;
    const int m0 = blockIdx.x * 64;
    const int cc = blockIdx.y;

#pragma unroll
    for (int t = 0; t < 2; ++t) {
        int idx4 = tid + t * 256;
        int r = idx4 >> 3, q = idx4 & 7;
        int n = m0 + r;
        float4 v = make_float4(0.f, 0.f, 0.f, 0.f);
        if (n < M) v = ((const float4*)A)[(size_t)n * 8 + q];
        As[q * 4 + 0][r] = v.x;
        As[q * 4 + 1][r] = v.y;
        As[q * 4 + 2][r] = v.z;
        As[q * 4 + 3][r] = v.w;
    }
#pragma unroll
    for (int i = tid; i < 32 * 64; i += 256) {
        int k = i >> 6, c = i & 63;
        Ws[k][c] = We[(size_t)k * HC + cc * 64 + c];
    }
    __syncthreads();

    const int rm = tid >> 4, rn = tid & 15;
    float acc[4][4];
#pragma unroll
    for (int i = 0; i < 4; ++i)
#pragma unroll
        for (int j = 0; j < 4; ++j) acc[i][j] = 0.f;
#pragma unroll
    for (int k = 0; k < 32; ++k) {
        float4 a = *(const float4*)&As[k][rm * 4];
        float4 bv = *(const float4*)&Ws[k][rn * 4];
        acc[0][0] += a.x * bv.x; acc[0][1] += a.x * bv.y;
        acc[0][2] += a.x * bv.z; acc[0][3] += a.x * bv.w;
        acc[1][0] += a.y * bv.x; acc[1][1] += a.y * bv.y;
        acc[1][2] += a.y * bv.z; acc[1][3] += a.y * bv.w;
        acc[2][0] += a.z * bv.x; acc[2][1] += a.z * bv.y;
        acc[2][2] += a.z * bv.z; acc[2][3] += a.z * bv.w;
        acc[3][0] += a.w * bv.x; acc[3][1] += a.w * bv.y;
        acc[3][2] += a.w * bv.z; acc[3][3] += a.w * bv.w;
    }
#pragma unroll
    for (int i = 0; i < 4; ++i) {
        int n = m0 + rm * 4 + i;
        if (n < M) {
            float4 o = make_float4(acc[i][0], acc[i][1], acc[i][2], acc[i][3]);
            *(float4*)&out[(size_t)n * HC + cc * 64 + rn * 4] = o;
        }
    }
}

// ---- fused edge logits in CSR order: GEMM + gather + att-dot + reduce ------
// block = 64 CSR positions; writes alpha contiguously; no atomics.
template <int H>
__global__ __launch_bounds__(256, 2) void k_fused(
        const float* __restrict__ xl, const float* __restrict__ xr,
        const float* __restrict__ ea,
        const int* __restrict__ cidx, const int* __restrict__ s_csr,
        const int* __restrict__ d_csr, int E,
        const float* __restrict__ We, const float* __restrict__ att,
        float* __restrict__ alpha) {
    constexpr int HC = H * 64;
    __shared__ float As[32][68];  // ea tile, [k][edge-row]
    __shared__ float Ws[32][64];  // We head chunk, [k][col]
    __shared__ int Es[64], Ss[64], Ds[64];
    const int tid = threadIdx.x;
    const int i0 = blockIdx.x * 64;

    if (tid < 64) {
        int i = i0 + tid;
        bool ok = i < E;
        Es[tid] = ok ? cidx[i] : 0;
        Ss[tid] = ok ? s_csr[i] : 0;
        Ds[tid] = ok ? d_csr[i] : 0;
    }
    __syncthreads();
#pragma unroll
    for (int t = 0; t < 2; ++t) {
        int idx4 = tid + t * 256;
        int r = idx4 >> 3, q = idx4 & 7;
        float4 v = make_float4(0.f, 0.f, 0.f, 0.f);
        if (i0 + r < E) v = ((const float4*)ea)[(size_t)Es[r] * 8 + q];
        As[q * 4 + 0][r] = v.x;
        As[q * 4 + 1][r] = v.y;
        As[q * 4 + 2][r] = v.z;
        As[q * 4 + 3][r] = v.w;
    }

    const int rm = tid >> 4, rn = tid & 15;

#pragma unroll
    for (int cc = 0; cc < H; ++cc) {
        __syncthreads();  // As/Ss ready (cc=0); prev chunk reads done (cc>0)
#pragma unroll
        for (int i = tid; i < 32 * 64; i += 256) {
            int k = i >> 6, c = i & 63;
            Ws[k][c] = We[(size_t)k * HC + cc * 64 + c];
        }
        __syncthreads();
        float acc[4][4];
#pragma unroll
        for (int i = 0; i < 4; ++i)
#pragma unroll
            for (int j = 0; j < 4; ++j) acc[i][j] = 0.f;
#pragma unroll
        for (int k = 0; k < 32; ++k) {
            float4 a = *(const float4*)&As[k][rm * 4];
            float4 bv = *(const float4*)&Ws[k][rn * 4];
            acc[0][0] += a.x * bv.x; acc[0][1] += a.x * bv.y;
            acc[0][2] += a.x * bv.z; acc[0][3] += a.x * bv.w;
            acc[1][0] += a.y * bv.x; acc[1][1] += a.y * bv.y;
            acc[1][2] += a.y * bv.z; acc[1][3] += a.y * bv.w;
            acc[2][0] += a.z * bv.x; acc[2][1] += a.z * bv.y;
            acc[2][2] += a.z * bv.z; acc[2][3] += a.z * bv.w;
            acc[3][0] += a.w * bv.x; acc[3][1] += a.w * bv.y;
            acc[3][2] += a.w * bv.z; acc[3][3] += a.w * bv.w;
        }
        float4 at4 = *(const float4*)&att[cc * 64 + rn * 4];
        float part[4];
#pragma unroll
        for (int i = 0; i < 4; ++i) {
            int s = Ss[rm * 4 + i], d = Ds[rm * 4 + i];
            float4 xa = *(const float4*)&xl[(size_t)s * HC + cc * 64 + rn * 4];
            float4 xb = *(const float4*)&xr[(size_t)d * HC + cc * 64 + rn * 4];
            float m0v = xa.x + xb.x + acc[i][0];
            float m1v = xa.y + xb.y + acc[i][1];
            float m2v = xa.z + xb.z + acc[i][2];
            float m3v = xa.w + xb.w + acc[i][3];
            m0v = m0v > 0.f ? m0v : 0.2f * m0v;
            m1v = m1v > 0.f ? m1v : 0.2f * m1v;
            m2v = m2v > 0.f ? m2v : 0.2f * m2v;
            m3v = m3v > 0.f ? m3v : 0.2f * m3v;
            part[i] = m0v * at4.x + m1v * at4.y + m2v * at4.z + m3v * at4.w;
        }
#pragma unroll
        for (int off = 1; off < 16; off <<= 1)
#pragma unroll
            for (int i = 0; i < 4; ++i) part[i] += __shfl_xor(part[i], off);
        if (rn == 0) {
#pragma unroll
            for (int i = 0; i < 4; ++i) {
                int gi = i0 + rm * 4 + i;
                if (gi < E) alpha[(size_t)gi * H + cc] = part[i];
            }
        }
    }
}

// self-loop logits: one wave per node; ee = EEself[n]/max(deg,1) by linearity
template <int H>
__global__ __launch_bounds__(256) void k_selfalpha(
        const float* __restrict__ xl, const float* __restrict__ xr,
        const float* __restrict__ EEself, const int* __restrict__ deg,
        const float* __restrict__ att,
        int Nn, float* __restrict__ aself) {
    constexpr int HC = H * 64;
    const int lane = threadIdx.x & 63;
    const int n = (blockIdx.x * blockDim.x + threadIdx.x) >> 6;
    if (n >= Nn) return;
    int dg = deg[n];
    float inv = 1.f / (float)(dg > 0 ? dg : 1);
    float al[H];
#pragma unroll
    for (int h = 0; h < H; ++h) {
        float m = xl[(size_t)n * HC + h * 64 + lane]
                + xr[(size_t)n * HC + h * 64 + lane]
                + EEself[(size_t)n * HC + h * 64 + lane] * inv;
        m = m > 0.f ? m : 0.2f * m;
        al[h] = m * att[h * 64 + lane];
    }
#pragma unroll
    for (int off = 1; off < 64; off <<= 1)
#pragma unroll
        for (int h = 0; h < H; ++h) al[h] += __shfl_xor(al[h], off);
    if (lane == 0) {
#pragma unroll
        for (int h = 0; h < H; ++h) aself[(size_t)n * H + h] = al[h];
    }
}

// online-softmax aggregate over CSR segment: one wave per node, lane = channel
template <int H, bool RELU>
__global__ __launch_bounds__(256, 2) void k_aggr(
        const float* __restrict__ xl,
        const int* __restrict__ s_csr, const int* __restrict__ row_ptr,
        const float* __restrict__ alpha, const float* __restrict__ aself,
        const float* __restrict__ bias, int Nn,
        float* __restrict__ out) {
    constexpr int HC = H * 64;
    const int lane = threadIdx.x & 63;
    const int n = (blockIdx.x * blockDim.x + threadIdx.x) >> 6;
    if (n >= Nn) return;
    float m[H], den[H], acc[H];
#pragma unroll
    for (int h = 0; h < H; ++h) {
        m[h] = aself[(size_t)n * H + h];   // self-loop seeds the online softmax
        den[h] = 1.f;
        acc[h] = xl[(size_t)n * HC + h * 64 + lane];
    }
    const int beg = row_ptr[n], end = row_ptr[n + 1];
    int i = beg;
    for (; i + 1 < end; i += 2) {
        int s0 = s_csr[i], s1 = s_csr[i + 1];
        float a0[H], a1[H], xv0[H], xv1[H];
#pragma unroll
        for (int h = 0; h < H; ++h) {
            a0[h] = alpha[(size_t)i * H + h];
            a1[h] = alpha[(size_t)(i + 1) * H + h];
            xv0[h] = xl[(size_t)s0 * HC + h * 64 + lane];
            xv1[h] = xl[(size_t)s1 * HC + h * 64 + lane];
        }
#pragma unroll
        for (int h = 0; h < H; ++h) {
            float nm = fmaxf(m[h], fmaxf(a0[h], a1[h]));
            float corr = __expf(m[h] - nm);
            float p0 = __expf(a0[h] - nm);
            float p1 = __expf(a1[h] - nm);
            den[h] = den[h] * corr + p0 + p1;
            acc[h] = acc[h] * corr + p0 * xv0[h] + p1 * xv1[h];
            m[h] = nm;
        }
    }
    if (i < end) {
        int s = s_csr[i];
#pragma unroll
        for (int h = 0; h < H; ++h) {
            float a = alpha[(size_t)i * H + h];
            float xv = xl[(size_t)s * HC + h * 64 + lane];
            float nm = fmaxf(m[h], a);
            float corr = __expf(m[h] - nm);
            float p = __expf(a - nm);
            den[h] = den[h] * corr + p;
            acc[h] = acc[h] * corr + p * xv;
            m[h] = nm;
        }
    }
#pragma unroll
    for (int h = 0; h < H; ++h) {
        float r = acc[h] / den[h] + bias[h * 64 + lane];
        if (RELU) r = r > 0.f ? r : 0.01f * r;
        out[(size_t)n * HC + h * 64 + lane] = r;
    }
}

// global_add_pool over sorted batch
__global__ void k_pool(const float* __restrict__ h2, const int* __restrict__ batch,
                       int Nn, float* __restrict__ g) {
    const int c = threadIdx.x;  // 0..191
    const int n0 = blockIdx.x * 128;
    if (n0 >= Nn) return;
    const int n1 = (n0 + 128 < Nn) ? n0 + 128 : Nn;
    float s = 0.f;
    int cur = batch[n0];
    for (int n = n0; n < n1; ++n) {
        int b = batch[n];
        if (b != cur) {
            atomicAdd(&g[cur * 192 + c], s);
            s = 0.f;
            cur = b;
        }
        s += h2[(size_t)n * 192 + c];
    }
    atomicAdd(&g[cur * 192 + c], s);
}

__global__ void k_mlp(const float* __restrict__ g,
                      const float* W1, const float* c1, const float* W2, const float* c2,
                      const float* W3, const float* c3, const float* W4, const float* c4,
                      const float* W5, const float* c5, const float* W6, const float* c6,
                      float* __restrict__ out) {
    __shared__ float t0[8 * 192];
    __shared__ float t1[8 * 64];
    __shared__ float t2[8 * 32];
    __shared__ float t3[8 * 16];
    __shared__ float t4[8 * 8];
    const int tid = threadIdx.x;
    for (int i = tid; i < 8 * 192; i += 256) t0[i] = g[i];
    __syncthreads();
    for (int i = tid; i < 8 * 64; i += 256) {
        int r = i >> 6, c = i & 63;
        float s = c1[c];
        for (int k = 0; k < 192; ++k) s += t0[r * 192 + k] * W1[k * 64 + c];
        t1[i] = s > 0.f ? s : 0.01f * s;
    }
    __syncthreads();
    for (int i = tid; i < 8 * 32; i += 256) {
        int r = i >> 5, c = i & 31;
        float s = c2[c];
        for (int k = 0; k < 64; ++k) s += t1[r * 64 + k] * W2[k * 32 + c];
        t2[i] = s > 0.f ? s : 0.01f * s;
    }
    __syncthreads();
    for (int i = tid; i < 8 * 16; i += 256) {
        int r = i >> 4, c = i & 15;
        float s = c3[c];
        for (int k = 0; k < 32; ++k) s += t2[r * 32 + k] * W3[k * 16 + c];
        t3[i] = s > 0.f ? s : 0.01f * s;
    }
    __syncthreads();
    for (int i = tid; i < 8 * 8; i += 256) {
        int r = i >> 3, c = i & 7;
        float s = c4[c];
        for (int k = 0; k < 16; ++k) s += t3[r * 16 + k] * W4[k * 8 + c];
        t4[i] = s > 0.f ? s : 0.01f * s;
    }
    __syncthreads();
    if (tid < 8) {
        float s = c5[0];
        for (int k = 0; k < 8; ++k) s += t4[tid * 8 + k] * W5[k];
        s = s * W6[0] + c6[0];
        out[tid] = s;
    }
}

extern "C" void kernel_launch(void* const* d_in, const int* in_sizes, int n_in,
                              void* d_out, int out_size, void* d_ws, size_t ws_size,
                              hipStream_t stream) {
    const float* x     = (const float*)d_in[0];
    const int*   eidx  = (const int*)d_in[1];
    const float* ea    = (const float*)d_in[2];
    const int*   batch = (const int*)d_in[3];
    const float* Wl1 = (const float*)d_in[4];
    const float* bl1 = (const float*)d_in[5];
    const float* Wr1 = (const float*)d_in[6];
    const float* br1 = (const float*)d_in[7];
    const float* We1 = (const float*)d_in[8];
    const float* att1 = (const float*)d_in[9];
    const float* bias1 = (const float*)d_in[10];
    const float* Wl2 = (const float*)d_in[11];
    const float* bl2 = (const float*)d_in[12];
    const float* Wr2 = (const float*)d_in[13];
    const float* br2 = (const float*)d_in[14];
    const float* We2 = (const float*)d_in[15];
    const float* att2 = (const float*)d_in[16];
    const float* bias2 = (const float*)d_in[17];
    const float* W1 = (const float*)d_in[18];
    const float* c1 = (const float*)d_in[19];
    const float* W2 = (const float*)d_in[20];
    const float* c2 = (const float*)d_in[21];
    const float* W3 = (const float*)d_in[22];
    const float* c3 = (const float*)d_in[23];
    const float* W4 = (const float*)d_in[24];
    const float* c4 = (const float*)d_in[25];
    const float* W5 = (const float*)d_in[26];
    const float* c5 = (const float*)d_in[27];
    const float* W6 = (const float*)d_in[28];
    const float* c6 = (const float*)d_in[29];

    const int N = in_sizes[0] / 128;
    const int E = in_sizes[1] / 2;
    const int* srcs = eidx;
    const int* dsts = eidx + E;

    char* p = (char*)d_ws;
    auto alloc = [&](size_t bytes) -> char* {
        char* r = p;
        p += (bytes + 255) & ~(size_t)255;
        return r;
    };
    int*      deg     = (int*)alloc((size_t)N * 4);
    int*      row_ptr = (int*)alloc((size_t)(N + 1) * 4);
    int*      woff    = (int*)alloc((size_t)N * 4);
    int*      cidx    = (int*)alloc((size_t)E * 4);
    int*      s_csr   = (int*)alloc((size_t)E * 4);
    int*      d_csr   = (int*)alloc((size_t)E * 4);
    int*      incl    = (int*)alloc((size_t)N * 4);
    int*      bsum    = (int*)alloc(64 * 4);
    float*    easum   = (float*)alloc((size_t)N * 32 * 4);
    float*    EEself  = (float*)alloc((size_t)N * 192 * 4);
    float*    xl      = (float*)alloc((size_t)N * 192 * 4);
    float*    xr      = (float*)alloc((size_t)N * 192 * 4);
    float*    h1      = (float*)alloc((size_t)N * 128 * 4);
    float*    h2      = (float*)alloc((size_t)N * 192 * 4);
    float*    alpha   = (float*)alloc((size_t)E * 3 * 4);
    float*    aself   = (float*)alloc((size_t)N * 3 * 4);
    float*    gp      = (float*)alloc(8 * 192 * 4);

    hipMemsetAsync(deg, 0, (size_t)N * 4, stream);
    hipMemsetAsync(gp, 0, 8 * 192 * 4, stream);

    // CSR build
    const int nb = (N + 2047) / 2048;
    k_deg<<<(E + 255) / 256, 256, 0, stream>>>(dsts, E, deg);
    k_scan1<<<nb, 256, 0, stream>>>(deg, N, incl, bsum);
    k_scan2<<<1, 64, 0, stream>>>(bsum, nb);
    k_scan3<<<(N + 255) / 256, 256, 0, stream>>>(incl, deg, bsum, N, row_ptr, woff);
    k_scatter<<<(E + 255) / 256, 256, 0, stream>>>(srcs, dsts, E, woff, cidx, s_csr, d_csr);

    const int mt = (N + 63) / 64;   // GEMM row tiles
    const int et = (E + 63) / 64;   // fused edge tiles
    const int nblk = (N + 3) / 4;   // node-parallel blocks (1 wave/node)

    k_easeg<<<nblk, 256, 0, stream>>>(ea, cidx, row_ptr, N, easum);

    // ---------------- conv1: H=2, HC=128 ----------------
    k_xw<128><<<dim3(mt, 2), 256, 0, stream>>>(x, N, Wl1, bl1, Wr1, br1, xl, xr);
    k_ee<128><<<dim3(mt, 2), 256, 0, stream>>>(easum, N, We1, EEself);
    k_selfalpha<2><<<nblk, 256, 0, stream>>>(xl, xr, EEself, deg, att1, N, aself);
    k_fused<2><<<et, 256, 0, stream>>>(xl, xr, ea, cidx, s_csr, d_csr, E, We1, att1, alpha);
    k_aggr<2, true><<<nblk, 256, 0, stream>>>(xl, s_csr, row_ptr, alpha, aself,
                                              bias1, N, h1);

    // ---------------- conv2: H=3, HC=192 ----------------
    k_xw<192><<<dim3(mt, 3), 256, 0, stream>>>(h1, N, Wl2, bl2, Wr2, br2, xl, xr);
    k_ee<192><<<dim3(mt, 3), 256, 0, stream>>>(easum, N, We2, EEself);
    k_selfalpha<3><<<nblk, 256, 0, stream>>>(xl, xr, EEself, deg, att2, N, aself);
    k_fused<3><<<et, 256, 0, stream>>>(xl, xr, ea, cidx, s_csr, d_csr, E, We2, att2, alpha);
    k_aggr<3, true><<<nblk, 256, 0, stream>>>(xl, s_csr, row_ptr, alpha, aself,
                                              bias2, N, h2);

    k_pool<<<(N + 127) / 128, 192, 0, stream>>>(h2, batch, N, gp);
    k_mlp<<<1, 256, 0, stream>>>(gp, W1, c1, W2, c2, W3, c3, W4, c4, W5, c5, W6, c6,
                                 (float*)d_out);
}

// Round 8
// 1181.271 us; speedup vs baseline: 2.4304x; 1.0559x over previous
//
#include <hip/hip_runtime.h>
#include <hip/hip_bf16.h>
#include <math.h>

// ---------------------------------------------------------------------------
// GATv2 x2 + global_add_pool + MLP head, fp32.
// CSR-ordered fused edge kernel: all-heads We staged once in LDS, barrier-free
// head loop (gathers pipeline under GEMM). Online-softmax aggregation.
// XCD-bijective block swizzle for L2 locality on gather kernels.
// ---------------------------------------------------------------------------

__device__ __forceinline__ int xcd_swizzle(int bid, int nwg) {
    int sq = nwg >> 3, sr = nwg & 7;
    int xcd = bid & 7, idx = bid >> 3;
    return (xcd < sr ? xcd * (sq + 1) : sr * (sq + 1) + (xcd - sr) * sq) + idx;
}

__global__ void k_deg(const int* __restrict__ dst, int E, int* __restrict__ deg) {
    int e = blockIdx.x * blockDim.x + threadIdx.x;
    if (e < E) atomicAdd(&deg[dst[e]], 1);
}

// ---- multi-block exclusive scan: deg[N] -> row_ptr[N+1], woff[N] ----------
__global__ void k_scan1(const int* __restrict__ deg, int N,
                        int* __restrict__ incl, int* __restrict__ bsum) {
    __shared__ int ws4[4];
    const int tid = threadIdx.x;
    const int lane = tid & 63, w = tid >> 6;
    const int base = blockIdx.x * 2048;
    int v[8];
    int s = 0;
#pragma unroll
    for (int j = 0; j < 8; ++j) {
        int i = base + tid * 8 + j;
        v[j] = (i < N) ? deg[i] : 0;
        s += v[j];
    }
    int ps = s;
#pragma unroll
    for (int off = 1; off < 64; off <<= 1) {
        int t = __shfl_up(ps, off);
        if (lane >= off) ps += t;
    }
    if (lane == 63) ws4[w] = ps;
    __syncthreads();
    int woffs = 0;
#pragma unroll
    for (int k = 0; k < 4; ++k)
        if (k < w) woffs += ws4[k];
    int run = ps - s + woffs;
#pragma unroll
    for (int j = 0; j < 8; ++j) {
        run += v[j];
        int i = base + tid * 8 + j;
        if (i < N) incl[i] = run;
    }
    if (tid == 255) bsum[blockIdx.x] = run;
}

__global__ void k_scan2(int* __restrict__ bsum, int nb) {
    if (threadIdx.x == 0) {
        int c = 0;
        for (int k = 0; k < nb; ++k) { int t = bsum[k]; bsum[k] = c; c += t; }
    }
}

__global__ void k_scan3(const int* __restrict__ incl, const int* __restrict__ deg,
                        const int* __restrict__ boff, int N,
                        int* __restrict__ row_ptr, int* __restrict__ woff) {
    int i = blockIdx.x * blockDim.x + threadIdx.x;
    if (i < N) {
        int v = incl[i] + boff[i >> 11];
        row_ptr[i + 1] = v;
        woff[i] = v - deg[i];
        if (i == 0) row_ptr[0] = 0;
    }
}

// scatter edges into CSR order; also materialize src/dst in CSR order
__global__ void k_scatter(const int* __restrict__ src, const int* __restrict__ dst,
                          int E, int* __restrict__ woff, int* __restrict__ cidx,
                          int* __restrict__ s_csr, int* __restrict__ d_csr) {
    int e = blockIdx.x * blockDim.x + threadIdx.x;
    if (e < E) {
        int d = dst[e];
        int p = atomicAdd(&woff[d], 1);
        cidx[p] = e;
        s_csr[p] = src[e];
        d_csr[p] = d;
    }
}

// segmented sum of edge attrs per dst (CSR order): one wave per node, lane<32
__global__ void k_easeg(const float* __restrict__ ea, const int* __restrict__ cidx,
                        const int* __restrict__ row_ptr, int N,
                        float* __restrict__ easum) {
    const int w = (blockIdx.x * blockDim.x + threadIdx.x) >> 6;
    const int lane = threadIdx.x & 63;
    if (w >= N || lane >= 32) return;
    const int beg = row_ptr[w], end = row_ptr[w + 1];
    float s = 0.f;
    for (int i = beg; i < end; ++i) {
        int e = cidx[i];
        s += ea[(size_t)e * 32 + lane];
    }
    easum[(size_t)w * 32 + lane] = s;
}

// ---- LDS-tiled GEMM: out{l,r}[n][col] = in[n][:128] . W{l,r}[:, col] + b ----
template <int HC>
__global__ __launch_bounds__(256, 2) void k_xw(
        const float* __restrict__ in, int N,
        const float* __restrict__ Wl, const float* __restrict__ bl,
        const float* __restrict__ Wr, const float* __restrict__ br,
        float* __restrict__ outl, float* __restrict__ outr) {
    __shared__ float Xs[128][68];  // [k][row], +4 pad
    __shared__ float Ws[128][64];  // [k][col]
    const int tid = threadIdx.x;
    const int m0 = blockIdx.x * 64;
    const int cc = blockIdx.y;

#pragma unroll
    for (int t = 0; t < 8; ++t) {
        int idx4 = tid + t * 256;
        int r = idx4 >> 5, k4 = idx4 & 31;
        int n = m0 + r;
        float4 v = make_float4(0.f, 0.f, 0.f, 0.f);
        if (n < N) v = ((const float4*)in)[(size_t)n * 32 + k4];
        Xs[k4 * 4 + 0][r] = v.x;
        Xs[k4 * 4 + 1][r] = v.y;
        Xs[k4 * 4 + 2][r] = v.z;
        Xs[k4 * 4 + 3][r] = v.w;
    }

    const int rm = tid >> 4, rn = tid & 15;
    float acc[4][4];

#pragma unroll
    for (int mat = 0; mat < 2; ++mat) {
        const float* W = mat ? Wr : Wl;
        const float* b = mat ? br : bl;
        float* out = mat ? outr : outl;
        __syncthreads();
#pragma unroll
        for (int i = tid; i < 128 * 64; i += 256) {
            int k = i >> 6, c = i & 63;
            Ws[k][c] = W[(size_t)k * HC + cc * 64 + c];
        }
        __syncthreads();
#pragma unroll
        for (int i = 0; i < 4; ++i)
#pragma unroll
            for (int j = 0; j < 4; ++j) acc[i][j] = 0.f;
#pragma unroll 8
        for (int k = 0; k < 128; ++k) {
            float4 a = *(const float4*)&Xs[k][rm * 4];
            float4 bv = *(const float4*)&Ws[k][rn * 4];
            acc[0][0] += a.x * bv.x; acc[0][1] += a.x * bv.y;
            acc[0][2] += a.x * bv.z; acc[0][3] += a.x * bv.w;
            acc[1][0] += a.y * bv.x; acc[1][1] += a.y * bv.y;
            acc[1][2] += a.y * bv.z; acc[1][3] += a.y * bv.w;
            acc[2][0] += a.z * bv.x; acc[2][1] += a.z * bv.y;
            acc[2][2] += a.z * bv.z; acc[2][3] += a.z * bv.w;
            acc[3][0] += a.w * bv.x; acc[3][1] += a.w * bv.y;
            acc[3][2] += a.w * bv.z; acc[3][3] += a.w * bv.w;
        }
        float4 bb = *(const float4*)&b[cc * 64 + rn * 4];
#pragma unroll
        for (int i = 0; i < 4; ++i) {
            int n = m0 + rm * 4 + i;
            if (n < N) {
                float4 o = make_float4(acc[i][0] + bb.x, acc[i][1] + bb.y,
                                       acc[i][2] + bb.z, acc[i][3] + bb.w);
                *(float4*)&out[(size_t)n * HC + cc * 64 + rn * 4] = o;
            }
        }
    }
}

// ---- EE GEMM (self-loop path): out[m][col] = A[m][:32] . We[:, col] --------
template <int HC>
__global__ __launch_bounds__(256, 2) void k_ee(
        const float* __restrict__ A, int M,
        const float* __restrict__ We,
        float* __restrict__ out) {
    __shared__ float As[32][68];
    __shared__ float Ws[32][64];
    const int tid = threadIdx.x;
    const int m0 = blockIdx.x * 64;
    const int cc = blockIdx.y;

#pragma unroll
    for (int t = 0; t < 2; ++t) {
        int idx4 = tid + t * 256;
        int r = idx4 >> 3, q = idx4 & 7;
        int n = m0 + r;
        float4 v = make_float4(0.f, 0.f, 0.f, 0.f);
        if (n < M) v = ((const float4*)A)[(size_t)n * 8 + q];
        As[q * 4 + 0][r] = v.x;
        As[q * 4 + 1][r] = v.y;
        As[q * 4 + 2][r] = v.z;
        As[q * 4 + 3][r] = v.w;
    }
#pragma unroll
    for (int i = tid; i < 32 * 64; i += 256) {
        int k = i >> 6, c = i & 63;
        Ws[k][c] = We[(size_t)k * HC + cc * 64 + c];
    }
    __syncthreads();

    const int rm = tid >> 4, rn = tid & 15;
    float acc[4][4];
#pragma unroll
    for (int i = 0; i < 4; ++i)
#pragma unroll
        for (int j = 0; j < 4; ++j) acc[i][j] = 0.f;
#pragma unroll
    for (int k = 0; k < 32; ++k) {
        float4 a = *(const float4*)&As[k][rm * 4];
        float4 bv = *(const float4*)&Ws[k][rn * 4];
        acc[0][0] += a.x * bv.x; acc[0][1] += a.x * bv.y;
        acc[0][2] += a.x * bv.z; acc[0][3] += a.x * bv.w;
        acc[1][0] += a.y * bv.x; acc[1][1] += a.y * bv.y;
        acc[1][2] += a.y * bv.z; acc[1][3] += a.y * bv.w;
        acc[2][0] += a.z * bv.x; acc[2][1] += a.z * bv.y;
        acc[2][2] += a.z * bv.z; acc[2][3] += a.z * bv.w;
        acc[3][0] += a.w * bv.x; acc[3][1] += a.w * bv.y;
        acc[3][2] += a.w * bv.z; acc[3][3] += a.w * bv.w;
    }
#pragma unroll
    for (int i = 0; i < 4; ++i) {
        int n = m0 + rm * 4 + i;
        if (n < M) {
            float4 o = make_float4(acc[i][0], acc[i][1], acc[i][2], acc[i][3]);
            *(float4*)&out[(size_t)n * HC + cc * 64 + rn * 4] = o;
        }
    }
}

// ---- fused edge logits in CSR order: GEMM + gather + att-dot + reduce ------
// block = 64 CSR positions; ALL heads' We staged once; barrier-free head loop.
template <int H>
__global__ __launch_bounds__(256, 2) void k_fused(
        const float* __restrict__ xl, const float* __restrict__ xr,
        const float* __restrict__ ea,
        const int* __restrict__ cidx, const int* __restrict__ s_csr,
        const int* __restrict__ d_csr, int E,
        const float* __restrict__ We, const float* __restrict__ att,
        float* __restrict__ alpha) {
    constexpr int HC = H * 64;
    __shared__ float As[32][68];       // ea tile, [k][edge-row]
    __shared__ float Ws[32][HC + 4];   // We, all heads
    __shared__ int Es[64], Ss[64], Ds[64];
    const int tid = threadIdx.x;
    const int wg = xcd_swizzle(blockIdx.x, gridDim.x);
    const int i0 = wg * 64;

    if (tid < 64) {
        int i = i0 + tid;
        bool ok = i < E;
        Es[tid] = ok ? cidx[i] : 0;
        Ss[tid] = ok ? s_csr[i] : 0;
        Ds[tid] = ok ? d_csr[i] : 0;
    }
    // stage all heads' We (vectorized; We is [32][HC] contiguous)
#pragma unroll
    for (int i4 = tid; i4 < 32 * (HC / 4); i4 += 256) {
        int k = i4 / (HC / 4), c4 = i4 % (HC / 4);
        float4 v = ((const float4*)We)[i4];
        *(float4*)&Ws[k][c4 * 4] = v;
    }
    __syncthreads();
    // stage ea tile (gathered rows via Es)
#pragma unroll
    for (int t = 0; t < 2; ++t) {
        int idx4 = tid + t * 256;
        int r = idx4 >> 3, q = idx4 & 7;
        float4 v = make_float4(0.f, 0.f, 0.f, 0.f);
        if (i0 + r < E) v = ((const float4*)ea)[(size_t)Es[r] * 8 + q];
        As[q * 4 + 0][r] = v.x;
        As[q * 4 + 1][r] = v.y;
        As[q * 4 + 2][r] = v.z;
        As[q * 4 + 3][r] = v.w;
    }
    __syncthreads();

    const int rm = tid >> 4, rn = tid & 15;

#pragma unroll
    for (int cc = 0; cc < H; ++cc) {
        float acc[4][4];
#pragma unroll
        for (int i = 0; i < 4; ++i)
#pragma unroll
            for (int j = 0; j < 4; ++j) acc[i][j] = 0.f;
#pragma unroll
        for (int k = 0; k < 32; ++k) {
            float4 a = *(const float4*)&As[k][rm * 4];
            float4 bv = *(const float4*)&Ws[k][cc * 64 + rn * 4];
            acc[0][0] += a.x * bv.x; acc[0][1] += a.x * bv.y;
            acc[0][2] += a.x * bv.z; acc[0][3] += a.x * bv.w;
            acc[1][0] += a.y * bv.x; acc[1][1] += a.y * bv.y;
            acc[1][2] += a.y * bv.z; acc[1][3] += a.y * bv.w;
            acc[2][0] += a.z * bv.x; acc[2][1] += a.z * bv.y;
            acc[2][2] += a.z * bv.z; acc[2][3] += a.z * bv.w;
            acc[3][0] += a.w * bv.x; acc[3][1] += a.w * bv.y;
            acc[3][2] += a.w * bv.z; acc[3][3] += a.w * bv.w;
        }
        float4 at4 = *(const float4*)&att[cc * 64 + rn * 4];
        float part[4];
#pragma unroll
        for (int i = 0; i < 4; ++i) {
            int s = Ss[rm * 4 + i], d = Ds[rm * 4 + i];
            float4 xa = *(const float4*)&xl[(size_t)s * HC + cc * 64 + rn * 4];
            float4 xb = *(const float4*)&xr[(size_t)d * HC + cc * 64 + rn * 4];
            float m0v = xa.x + xb.x + acc[i][0];
            float m1v = xa.y + xb.y + acc[i][1];
            float m2v = xa.z + xb.z + acc[i][2];
            float m3v = xa.w + xb.w + acc[i][3];
            m0v = m0v > 0.f ? m0v : 0.2f * m0v;
            m1v = m1v > 0.f ? m1v : 0.2f * m1v;
            m2v = m2v > 0.f ? m2v : 0.2f * m2v;
            m3v = m3v > 0.f ? m3v : 0.2f * m3v;
            part[i] = m0v * at4.x + m1v * at4.y + m2v * at4.z + m3v * at4.w;
        }
#pragma unroll
        for (int off = 1; off < 16; off <<= 1)
#pragma unroll
            for (int i = 0; i < 4; ++i) part[i] += __shfl_xor(part[i], off);
        if (rn == 0) {
#pragma unroll
            for (int i = 0; i < 4; ++i) {
                int gi = i0 + rm * 4 + i;
                if (gi < E) alpha[(size_t)gi * H + cc] = part[i];
            }
        }
    }
}

// self-loop logits: one wave per node; ee = EEself[n]/max(deg,1) by linearity
template <int H>
__global__ __launch_bounds__(256) void k_selfalpha(
        const float* __restrict__ xl, const float* __restrict__ xr,
        const float* __restrict__ EEself, const int* __restrict__ deg,
        const float* __restrict__ att,
        int Nn, float* __restrict__ aself) {
    constexpr int HC = H * 64;
    const int lane = threadIdx.x & 63;
    const int n = (blockIdx.x * blockDim.x + threadIdx.x) >> 6;
    if (n >= Nn) return;
    int dg = deg[n];
    float inv = 1.f / (float)(dg > 0 ? dg : 1);
    float al[H];
#pragma unroll
    for (int h = 0; h < H; ++h) {
        float m = xl[(size_t)n * HC + h * 64 + lane]
                + xr[(size_t)n * HC + h * 64 + lane]
                + EEself[(size_t)n * HC + h * 64 + lane] * inv;
        m = m > 0.f ? m : 0.2f * m;
        al[h] = m * att[h * 64 + lane];
    }
#pragma unroll
    for (int off = 1; off < 64; off <<= 1)
#pragma unroll
        for (int h = 0; h < H; ++h) al[h] += __shfl_xor(al[h], off);
    if (lane == 0) {
#pragma unroll
        for (int h = 0; h < H; ++h) aself[(size_t)n * H + h] = al[h];
    }
}

// online-softmax aggregate over CSR segment: one wave per node, lane = channel
template <int H, bool RELU>
__global__ __launch_bounds__(256, 2) void k_aggr(
        const float* __restrict__ xl,
        const int* __restrict__ s_csr, const int* __restrict__ row_ptr,
        const float* __restrict__ alpha, const float* __restrict__ aself,
        const float* __restrict__ bias, int Nn,
        float* __restrict__ out) {
    constexpr int HC = H * 64;
    const int lane = threadIdx.x & 63;
    const int wg = xcd_swizzle(blockIdx.x, gridDim.x);
    const int n = wg * 4 + ((int)threadIdx.x >> 6);
    if (n >= Nn) return;
    float m[H], den[H], acc[H];
#pragma unroll
    for (int h = 0; h < H; ++h) {
        m[h] = aself[(size_t)n * H + h];   // self-loop seeds the online softmax
        den[h] = 1.f;
        acc[h] = xl[(size_t)n * HC + h * 64 + lane];
    }
    const int beg = row_ptr[n], end = row_ptr[n + 1];
    int i = beg;
    for (; i + 1 < end; i += 2) {
        int s0 = s_csr[i], s1 = s_csr[i + 1];
        float a0[H], a1[H], xv0[H], xv1[H];
#pragma unroll
        for (int h = 0; h < H; ++h) {
            a0[h] = alpha[(size_t)i * H + h];
            a1[h] = alpha[(size_t)(i + 1) * H + h];
            xv0[h] = xl[(size_t)s0 * HC + h * 64 + lane];
            xv1[h] = xl[(size_t)s1 * HC + h * 64 + lane];
        }
#pragma unroll
        for (int h = 0; h < H; ++h) {
            float nm = fmaxf(m[h], fmaxf(a0[h], a1[h]));
            float corr = __expf(m[h] - nm);
            float p0 = __expf(a0[h] - nm);
            float p1 = __expf(a1[h] - nm);
            den[h] = den[h] * corr + p0 + p1;
            acc[h] = acc[h] * corr + p0 * xv0[h] + p1 * xv1[h];
            m[h] = nm;
        }
    }
    if (i < end) {
        int s = s_csr[i];
#pragma unroll
        for (int h = 0; h < H; ++h) {
            float a = alpha[(size_t)i * H + h];
            float xv = xl[(size_t)s * HC + h * 64 + lane];
            float nm = fmaxf(m[h], a);
            float corr = __expf(m[h] - nm);
            float p = __expf(a - nm);
            den[h] = den[h] * corr + p;
            acc[h] = acc[h] * corr + p * xv;
            m[h] = nm;
        }
    }
#pragma unroll
    for (int h = 0; h < H; ++h) {
        float r = acc[h] / den[h] + bias[h * 64 + lane];
        if (RELU) r = r > 0.f ? r : 0.01f * r;
        out[(size_t)n * HC + h * 64 + lane] = r;
    }
}

// global_add_pool over sorted batch
__global__ void k_pool(const float* __restrict__ h2, const int* __restrict__ batch,
                       int Nn, float* __restrict__ g) {
    const int c = threadIdx.x;  // 0..191
    const int n0 = blockIdx.x * 128;
    if (n0 >= Nn) return;
    const int n1 = (n0 + 128 < Nn) ? n0 + 128 : Nn;
    float s = 0.f;
    int cur = batch[n0];
    for (int n = n0; n < n1; ++n) {
        int b = batch[n];
        if (b != cur) {
            atomicAdd(&g[cur * 192 + c], s);
            s = 0.f;
            cur = b;
        }
        s += h2[(size_t)n * 192 + c];
    }
    atomicAdd(&g[cur * 192 + c], s);
}

__global__ void k_mlp(const float* __restrict__ g,
                      const float* W1, const float* c1, const float* W2, const float* c2,
                      const float* W3, const float* c3, const float* W4, const float* c4,
                      const float* W5, const float* c5, const float* W6, const float* c6,
                      float* __restrict__ out) {
    __shared__ float t0[8 * 192];
    __shared__ float t1[8 * 64];
    __shared__ float t2[8 * 32];
    __shared__ float t3[8 * 16];
    __shared__ float t4[8 * 8];
    const int tid = threadIdx.x;
    for (int i = tid; i < 8 * 192; i += 256) t0[i] = g[i];
    __syncthreads();
    for (int i = tid; i < 8 * 64; i += 256) {
        int r = i >> 6, c = i & 63;
        float s = c1[c];
        for (int k = 0; k < 192; ++k) s += t0[r * 192 + k] * W1[k * 64 + c];
        t1[i] = s > 0.f ? s : 0.01f * s;
    }
    __syncthreads();
    for (int i = tid; i < 8 * 32; i += 256) {
        int r = i >> 5, c = i & 31;
        float s = c2[c];
        for (int k = 0; k < 64; ++k) s += t1[r * 64 + k] * W2[k * 32 + c];
        t2[i] = s > 0.f ? s : 0.01f * s;
    }
    __syncthreads();
    for (int i = tid; i < 8 * 16; i += 256) {
        int r = i >> 4, c = i & 15;
        float s = c3[c];
        for (int k = 0; k < 32; ++k) s += t2[r * 32 + k] * W3[k * 16 + c];
        t3[i] = s > 0.f ? s : 0.01f * s;
    }
    __syncthreads();
    for (int i = tid; i < 8 * 8; i += 256) {
        int r = i >> 3, c = i & 7;
        float s = c4[c];
        for (int k = 0; k < 16; ++k) s += t3[r * 16 + k] * W4[k * 8 + c];
        t4[i] = s > 0.f ? s : 0.01f * s;
    }
    __syncthreads();
    if (tid < 8) {
        float s = c5[0];
        for (int k = 0; k < 8; ++k) s += t4[tid * 8 + k] * W5[k];
        s = s * W6[0] + c6[0];
        out[tid] = s;
    }
}

extern "C" void kernel_launch(void* const* d_in, const int* in_sizes, int n_in,
                              void* d_out, int out_size, void* d_ws, size_t ws_size,
                              hipStream_t stream) {
    const float* x     = (const float*)d_in[0];
    const int*   eidx  = (const int*)d_in[1];
    const float* ea    = (const float*)d_in[2];
    const int*   batch = (const int*)d_in[3];
    const float* Wl1 = (const float*)d_in[4];
    const float* bl1 = (const float*)d_in[5];
    const float* Wr1 = (const float*)d_in[6];
    const float* br1 = (const float*)d_in[7];
    const float* We1 = (const float*)d_in[8];
    const float* att1 = (const float*)d_in[9];
    const float* bias1 = (const float*)d_in[10];
    const float* Wl2 = (const float*)d_in[11];
    const float* bl2 = (const float*)d_in[12];
    const float* Wr2 = (const float*)d_in[13];
    const float* br2 = (const float*)d_in[14];
    const float* We2 = (const float*)d_in[15];
    const float* att2 = (const float*)d_in[16];
    const float* bias2 = (const float*)d_in[17];
    const float* W1 = (const float*)d_in[18];
    const float* c1 = (const float*)d_in[19];
    const float* W2 = (const float*)d_in[20];
    const float* c2 = (const float*)d_in[21];
    const float* W3 = (const float*)d_in[22];
    const float* c3 = (const float*)d_in[23];
    const float* W4 = (const float*)d_in[24];
    const float* c4 = (const float*)d_in[25];
    const float* W5 = (const float*)d_in[26];
    const float* c5 = (const float*)d_in[27];
    const float* W6 = (const float*)d_in[28];
    const float* c6 = (const float*)d_in[29];

    const int N = in_sizes[0] / 128;
    const int E = in_sizes[1] / 2;
    const int* srcs = eidx;
    const int* dsts = eidx + E;

    char* p = (char*)d_ws;
    auto alloc = [&](size_t bytes) -> char* {
        char* r = p;
        p += (bytes + 255) & ~(size_t)255;
        return r;
    };
    int*      deg     = (int*)alloc((size_t)N * 4);
    int*      row_ptr = (int*)alloc((size_t)(N + 1) * 4);
    int*      woff    = (int*)alloc((size_t)N * 4);
    int*      cidx    = (int*)alloc((size_t)E * 4);
    int*      s_csr   = (int*)alloc((size_t)E * 4);
    int*      d_csr   = (int*)alloc((size_t)E * 4);
    int*      incl    = (int*)alloc((size_t)N * 4);
    int*      bsum    = (int*)alloc(64 * 4);
    float*    easum   = (float*)alloc((size_t)N * 32 * 4);
    float*    EEself  = (float*)alloc((size_t)N * 192 * 4);
    float*    xl      = (float*)alloc((size_t)N * 192 * 4);
    float*    xr      = (float*)alloc((size_t)N * 192 * 4);
    float*    h1      = (float*)alloc((size_t)N * 128 * 4);
    float*    h2      = (float*)alloc((size_t)N * 192 * 4);
    float*    alpha   = (float*)alloc((size_t)E * 3 * 4);
    float*    aself   = (float*)alloc((size_t)N * 3 * 4);
    float*    gp      = (float*)alloc(8 * 192 * 4);

    hipMemsetAsync(deg, 0, (size_t)N * 4, stream);
    hipMemsetAsync(gp, 0, 8 * 192 * 4, stream);

    // CSR build
    const int nb = (N + 2047) / 2048;
    k_deg<<<(E + 255) / 256, 256, 0, stream>>>(dsts, E, deg);
    k_scan1<<<nb, 256, 0, stream>>>(deg, N, incl, bsum);
    k_scan2<<<1, 64, 0, stream>>>(bsum, nb);
    k_scan3<<<(N + 255) / 256, 256, 0, stream>>>(incl, deg, bsum, N, row_ptr, woff);
    k_scatter<<<(E + 255) / 256, 256, 0, stream>>>(srcs, dsts, E, woff, cidx, s_csr, d_csr);

    const int mt = (N + 63) / 64;   // GEMM row tiles
    const int et = (E + 63) / 64;   // fused edge tiles
    const int nblk = (N + 3) / 4;   // node-parallel blocks (1 wave/node)

    k_easeg<<<nblk, 256, 0, stream>>>(ea, cidx, row_ptr, N, easum);

    // ---------------- conv1: H=2, HC=128 ----------------
    k_xw<128><<<dim3(mt, 2), 256, 0, stream>>>(x, N, Wl1, bl1, Wr1, br1, xl, xr);
    k_ee<128><<<dim3(mt, 2), 256, 0, stream>>>(easum, N, We1, EEself);
    k_selfalpha<2><<<nblk, 256, 0, stream>>>(xl, xr, EEself, deg, att1, N, aself);
    k_fused<2><<<et, 256, 0, stream>>>(xl, xr, ea, cidx, s_csr, d_csr, E, We1, att1, alpha);
    k_aggr<2, true><<<nblk, 256, 0, stream>>>(xl, s_csr, row_ptr, alpha, aself,
                                              bias1, N, h1);

    // ---------------- conv2: H=3, HC=192 ----------------
    k_xw<192><<<dim3(mt, 3), 256, 0, stream>>>(h1, N, Wl2, bl2, Wr2, br2, xl, xr);
    k_ee<192><<<dim3(mt, 3), 256, 0, stream>>>(easum, N, We2, EEself);
    k_selfalpha<3><<<nblk, 256, 0, stream>>>(xl, xr, EEself, deg, att2, N, aself);
    k_fused<3><<<et, 256, 0, stream>>>(xl, xr, ea, cidx, s_csr, d_csr, E, We2, att2, alpha);
    k_aggr<3, true><<<nblk, 256, 0, stream>>>(xl, s_csr, row_ptr, alpha, aself,
                                              bias2, N, h2);

    k_pool<<<(N + 127) / 128, 192, 0, stream>>>(h2, batch, N, gp);
    k_mlp<<<1, 256, 0, stream>>>(gp, W1, c1, W2, c2, W3, c3, W4, c4, W5, c5, W6, c6,
                                 (float*)d_out);
}